// Round 11
// baseline (401.746 us; speedup 1.0000x reference)
//
#include <hip/hip_runtime.h>
#include <hip/hip_bf16.h>

using bf16 = __hip_bfloat16;

#define DI __device__ __forceinline__

typedef __attribute__((ext_vector_type(8))) short short8;
typedef __attribute__((ext_vector_type(8))) unsigned short u16x8;
typedef __attribute__((ext_vector_type(4))) unsigned short u16x4;
typedef __attribute__((ext_vector_type(4))) float f32x4;

#define MFMA_BF16 __builtin_amdgcn_mfma_f32_16x16x32_bf16

DI float leaky(float x) { return x > 0.f ? x : 0.1f * x; }

// bf16 split helpers (RNE). x = hi + lo to ~2^-16 relative.
DI unsigned short b16(float x) {
  union { float f; unsigned u; } v; v.f = x;
  unsigned r = v.u + 0x7FFFu + ((v.u >> 16) & 1u);
  return (unsigned short)(r >> 16);
}
DI float fromb16(unsigned short h) {
  union { unsigned u; float f; } v; v.u = ((unsigned)h) << 16; return v.f;
}

// Problem constants: B=2, C=64, H=64, W=64, N=4096
// Inputs are fp32 (established R3/R4).
static constexpr int N_ = 4096;
static constexpr size_t CN = 262144;
static constexpr size_t BCN = 524288;

// ---- Workspace layout (float indices) ----
static constexpr size_t XG_OFF = 137104;
static constexpr size_t GG_OFF = XG_OFF + BCN;
static constexpr size_t QX_OFF = GG_OFF + BCN;
static constexpr size_t KX_OFF = QX_OFF + BCN;
static constexpr size_t VX_OFF = KX_OFF + BCN;
static constexpr size_t QG_OFF = VX_OFF + BCN;
static constexpr size_t KG_OFF = QG_OFF + BCN;
static constexpr size_t P1X_OFF = KG_OFF + BCN;
static constexpr size_t P1G_OFF = P1X_OFF + BCN;
static constexpr size_t ML_OFF  = P1G_OFF + BCN;
static constexpr size_t MLL_OFF = ML_OFF + 32768;
static constexpr size_t OB_OFF = QX_OFF;
static constexpr size_t UB_OFF = KX_OFF;
static constexpr size_t GO_OFF = GG_OFF;
static constexpr size_t QXH_U = QX_OFF * 2, QXL_U = QXH_U + BCN;
static constexpr size_t KXH_U = KX_OFF * 2, KXL_U = KXH_U + BCN;
static constexpr size_t VXH_U = VX_OFF * 2, VXL_U = VXH_U + BCN;
static constexpr size_t QGH_U = QG_OFF * 2, QGL_U = QGH_U + BCN;
static constexpr size_t KGH_U = KG_OFF * 2, KGL_U = KGH_U + BCN;
// Peak 19.7 MB (validated R6-R10)

// ---- conv tile constants: 16 output rows x 64 cols, 18 input rows, stride 68 ----
static constexpr int TRS = 68;

DI float4 cc_stage(const float* in, int b, int ch, int hh, int ci) {
  float4 v = make_float4(0.f, 0.f, 0.f, 0.f);
  if (hh >= 0 && hh < 64) {
    if (ch < 64) {
      v = *reinterpret_cast<const float4*>(in + ((size_t)(b * 64 + ch)) * N_ + (size_t)hh * 64 + ci);
    } else if (ch == 64) {
      v.x = (float)ci * (2.f / 63.f) - 1.f;       v.y = (float)(ci + 1) * (2.f / 63.f) - 1.f;
      v.z = (float)(ci + 2) * (2.f / 63.f) - 1.f; v.w = (float)(ci + 3) * (2.f / 63.f) - 1.f;
    } else {
      float y = (float)hh * (2.f / 63.f) - 1.f;
      v = make_float4(y, y, y, y);
    }
  }
  return v;
}

// ---------------- K1: coord-conv 3x3 + inline channel attention (2 oc/block) ----------------
__global__ __launch_bounds__(256) void k_coordconv(const float* __restrict__ x,
                                                   const float* __restrict__ g,
                                                   const float* __restrict__ lw_p,
                                                   const float* __restrict__ lb_p,
                                                   const float* __restrict__ cw,
                                                   float* __restrict__ ws) {
  int blk = blockIdx.x;  // 512 = src*256 + b*128 + og*4 + rt
  int rt = blk & 3;   blk >>= 2;
  int og = blk & 31;  blk >>= 5;
  int b  = blk & 1;   blk >>= 1;
  int src = blk;
  int o0 = og * 2;
  int h0 = rt * 16;
  const float* in = src ? g : x;
  float* outp = ws + (src ? GG_OFF : XG_OFF);
  __shared__ __align__(16) float wl[1188];          // [ch][tap][oo], oo=2
  __shared__ __align__(16) float tile[2][18 * TRS];
  __shared__ float sCA[2];
  int t = threadIdx.x;

  // channel attention for this block's 2 output channels (waves 0,1)
  {
    int wv = t >> 6, lane = t & 63;
    if (wv < 2) {
      const float* chp = in + ((size_t)(b * 64 + o0 + wv)) * N_;
      float s = 0.f;
      for (int i = lane; i < N_; i += 64) s += chp[i];
#pragma unroll
      for (int d = 1; d < 64; d <<= 1) s += __shfl_xor(s, d, 64);
      if (lane == 0) {
        float p = s * (1.f / (float)N_);
        float lwv = lw_p[0], lbv = lb_p[0];
        float h = leaky(lwv * p + lbv);
        sCA[wv] = 1.f / (1.f + expf(-(lwv * h + lbv)));
      }
    }
  }

  for (int idx = t; idx < 1188; idx += 256) {
    int ch = idx / 18, rr = idx % 18;
    int k = rr >> 1, oo = rr & 1;
    wl[idx] = cw[(size_t)(o0 + oo) * 594 + ch * 9 + k];
  }
  int r = t >> 4, c0 = (t & 15) * 4;
  int ria = t >> 4, cia = (t & 15) * 4;
  int rib2 = 16 + (t >> 4);
  bool hasb = (t < 32);
  float4 pfa = cc_stage(in, b, 0, h0 - 1 + ria, cia);
  float4 pfb = hasb ? cc_stage(in, b, 0, h0 - 1 + rib2, cia) : make_float4(0, 0, 0, 0);
  float acc[2][4] = {};
  for (int ch = 0; ch < 66; ++ch) {
    float* buf = tile[ch & 1];
    *reinterpret_cast<float4*>(&buf[ria * TRS + cia]) = pfa;
    if (hasb) *reinterpret_cast<float4*>(&buf[rib2 * TRS + cia]) = pfb;
    if (ch + 1 < 66) {
      pfa = cc_stage(in, b, ch + 1, h0 - 1 + ria, cia);
      if (hasb) pfb = cc_stage(in, b, ch + 1, h0 - 1 + rib2, cia);
    }
    __syncthreads();
#pragma unroll
    for (int ky = 0; ky < 3; ++ky) {
      int base = (r + ky) * TRS;
      float4 m = *reinterpret_cast<const float4*>(&buf[base + c0]);
      float left = (c0 > 0) ? buf[base + c0 - 1] : 0.f;
      float right = (c0 < 60) ? buf[base + c0 + 4] : 0.f;
      float t6[6] = {left, m.x, m.y, m.z, m.w, right};
#pragma unroll
      for (int kx = 0; kx < 3; ++kx) {
        float2 w2 = *reinterpret_cast<const float2*>(&wl[ch * 18 + (ky * 3 + kx) * 2]);
#pragma unroll
        for (int j = 0; j < 4; ++j) {
          float tp = t6[kx + j];
          acc[0][j] = fmaf(w2.x, tp, acc[0][j]);
          acc[1][j] = fmaf(w2.y, tp, acc[1][j]);
        }
      }
    }
  }
  size_t opix = (size_t)(h0 + r) * 64 + c0;
#pragma unroll
  for (int oo = 0; oo < 2; ++oo) {
    float s = sCA[oo];
    float4 o = make_float4(acc[oo][0] * s, acc[oo][1] * s, acc[oo][2] * s, acc[oo][3] * s);
    *reinterpret_cast<float4*>(outp + ((size_t)(b * 64 + o0 + oo)) * N_ + opix) = o;
  }
}

// ---------------- K2: 1x1 projections; outputs pre-split bf16 hi/lo ----------------
__global__ __launch_bounds__(256) void k_proj(float* __restrict__ ws,
                                              const float* __restrict__ xqw, const float* __restrict__ xqb,
                                              const float* __restrict__ xkw, const float* __restrict__ xkb,
                                              const float* __restrict__ xvw, const float* __restrict__ xvb,
                                              const float* __restrict__ gqw, const float* __restrict__ gqb,
                                              const float* __restrict__ gkw, const float* __restrict__ gkb) {
  int blk = blockIdx.x;  // 5 * 2 * 64
  int pt = blk & 63; blk >>= 6;
  int b  = blk & 1;  blk >>= 1;
  int which = blk;
  size_t in_o;
  const float *wp, *bp;
  size_t hU = 0, lU = 0;
  if (which == 0)      { in_o = XG_OFF; wp = xqw; bp = xqb; hU = QXH_U; lU = QXL_U; }
  else if (which == 1) { in_o = XG_OFF; wp = xkw; bp = xkb; hU = KXH_U; lU = KXL_U; }
  else if (which == 2) { in_o = XG_OFF; wp = xvw; bp = xvb; }
  else if (which == 3) { in_o = GG_OFF; wp = gqw; bp = gqb; hU = QGH_U; lU = QGL_U; }
  else                 { in_o = GG_OFF; wp = gkw; bp = gkb; hU = KGH_U; lU = KGL_U; }

  __shared__ float tile[64 * 64];
  __shared__ float wl[64 * 65];
  __shared__ float bl[64];
  unsigned short* us = (unsigned short*)ws;
  int t = threadIdx.x;
  int pb = pt * 64;
  const float* in0 = ws + in_o + (size_t)b * CN + pb;
  for (int c0 = (t >> 6); c0 < 64; c0 += 4)
    tile[c0 * 64 + (t & 63)] = in0[(size_t)c0 * N_ + (t & 63)];
  for (int idx = t; idx < 4096; idx += 256)
    wl[(idx >> 6) * 65 + (idx & 63)] = wp[idx];
  if (t < 64) bl[t] = bp[t];
  __syncthreads();
  int o = t & 63, grp = t >> 6;
  const float* wr = &wl[o * 65];
  float acc[16];
  float bv = bl[o];
#pragma unroll
  for (int j = 0; j < 16; ++j) acc[j] = bv;
  for (int c = 0; c < 64; ++c) {
    float wv = wr[c];
    const float4* tb = reinterpret_cast<const float4*>(&tile[c * 64 + grp * 16]);
    float4 t0 = tb[0], t1 = tb[1], t2 = tb[2], t3 = tb[3];
    acc[0] = fmaf(wv, t0.x, acc[0]);   acc[1] = fmaf(wv, t0.y, acc[1]);
    acc[2] = fmaf(wv, t0.z, acc[2]);   acc[3] = fmaf(wv, t0.w, acc[3]);
    acc[4] = fmaf(wv, t1.x, acc[4]);   acc[5] = fmaf(wv, t1.y, acc[5]);
    acc[6] = fmaf(wv, t1.z, acc[6]);   acc[7] = fmaf(wv, t1.w, acc[7]);
    acc[8] = fmaf(wv, t2.x, acc[8]);   acc[9] = fmaf(wv, t2.y, acc[9]);
    acc[10] = fmaf(wv, t2.z, acc[10]); acc[11] = fmaf(wv, t2.w, acc[11]);
    acc[12] = fmaf(wv, t3.x, acc[12]); acc[13] = fmaf(wv, t3.y, acc[13]);
    acc[14] = fmaf(wv, t3.z, acc[14]); acc[15] = fmaf(wv, t3.w, acc[15]);
  }
  if (which != 2) {
#pragma unroll
    for (int j = 0; j < 16; ++j) {
      size_t idx = ((size_t)b * N_ + pb + grp * 16 + j) * 64 + o;
      unsigned short hi = b16(acc[j]);
      us[hU + idx] = hi;
      us[lU + idx] = b16(acc[j] - fromb16(hi));
    }
  } else {
    __syncthreads();
    float* ot = wl;
#pragma unroll
    for (int j = 0; j < 16; ++j) ot[o * 65 + grp * 16 + j] = acc[j];
    __syncthreads();
    int o2 = t >> 2;
#pragma unroll
    for (int e = 0; e < 4; ++e) {
      int px = (t & 3) * 16 + e * 4;
      u16x4 hv, lv;
#pragma unroll
      for (int q = 0; q < 4; ++q) {
        float v = ot[o2 * 65 + px + q];
        unsigned short hi = b16(v);
        hv[q] = hi; lv[q] = b16(v - fromb16(hi));
      }
      size_t idx = ((size_t)(b * 64 + o2)) * N_ + pb + px;
      *reinterpret_cast<u16x4*>(&us[VXH_U + idx]) = hv;
      *reinterpret_cast<u16x4*>(&us[VXL_U + idx]) = lv;
    }
  }
}

// ---------------- K3: MFMA flash attention (pre-split inputs, reg-prefetch dbuf) ----------------
__global__ __launch_bounds__(256) void k_attn(float* __restrict__ ws) {
  unsigned short* us = (unsigned short*)ws;
  int blk = blockIdx.x;
  int half = blk & 1; blk >>= 1;
  int qt = blk & 63;  blk >>= 6;
  int b  = blk & 1;   blk >>= 1;
  int at = blk;
  const unsigned short* QH = us + (at ? QGH_U : QXH_U);
  const unsigned short* QL = us + (at ? QGL_U : QXL_U);
  const unsigned short* KHg = us + (at ? KGH_U : KXH_U);
  const unsigned short* KLg = us + (at ? KGL_U : KXL_U);
  const unsigned short* VHg = us + VXH_U;
  const unsigned short* VLg = us + VXL_U;
  float* Pg = ws + (at ? (half ? P1G_OFF : GG_OFF) : (half ? P1X_OFF : XG_OFF))
            + (size_t)b * CN + qt * 64;

  __shared__ unsigned short Kh[4096], Kl[4096], Vth[4096], Vtl[4096], Ph[4096], Pl[4096];
  __shared__ float sAl[64];

  int t = threadIdx.x;
  int w = t >> 6, lane = t & 63, quad = lane >> 4, l15 = lane & 15;
  int swz = l15 & 7;

  short8 qh[2], ql[2];
  {
    size_t qbase = ((size_t)b * N_ + qt * 64 + 16 * w + l15) * 64;
#pragma unroll
    for (int ks = 0; ks < 2; ++ks) {
      qh[ks] = *reinterpret_cast<const short8*>(&QH[qbase + ks * 32 + quad * 8]);
      ql[ks] = *reinterpret_cast<const short8*>(&QL[qbase + ks * 32 + quad * 8]);
    }
  }

  u16x8 rkh[2], rkl[2], rvh[2], rvl[2];
  auto prefetch = [&](int mt) {
#pragma unroll
    for (int it = 0; it < 2; ++it) {
      int f8 = it * 256 + t;
      int r = f8 >> 3, ch = f8 & 7;
      size_t kgi = ((size_t)b * N_ + mt * 64 + r) * 64 + ch * 8;
      rkh[it] = *reinterpret_cast<const u16x8*>(&KHg[kgi]);
      rkl[it] = *reinterpret_cast<const u16x8*>(&KLg[kgi]);
      size_t vgi = ((size_t)(b * 64 + r)) * N_ + mt * 64 + ch * 8;
      rvh[it] = *reinterpret_cast<const u16x8*>(&VHg[vgi]);
      rvl[it] = *reinterpret_cast<const u16x8*>(&VLg[vgi]);
    }
  };

  f32x4 Oa[4] = {{0.f, 0.f, 0.f, 0.f}, {0.f, 0.f, 0.f, 0.f},
                 {0.f, 0.f, 0.f, 0.f}, {0.f, 0.f, 0.f, 0.f}};
  float M[4] = {-1e30f, -1e30f, -1e30f, -1e30f};
  float L[4] = {0.f, 0.f, 0.f, 0.f};

  int mt0 = half * 32, mt1 = half * 32 + 32;
  prefetch(mt0);
  for (int mt = mt0; mt < mt1; ++mt) {
    __syncthreads();
#pragma unroll
    for (int it = 0; it < 2; ++it) {
      int f8 = it * 256 + t;
      int r = f8 >> 3, ch = f8 & 7;
      int off = r * 64 + ((ch ^ (r & 7)) << 3);
      *reinterpret_cast<u16x8*>(&Kh[off]) = rkh[it];
      *reinterpret_cast<u16x8*>(&Kl[off]) = rkl[it];
      *reinterpret_cast<u16x8*>(&Vth[off]) = rvh[it];
      *reinterpret_cast<u16x8*>(&Vtl[off]) = rvl[it];
    }
    if (mt + 1 < mt1) prefetch(mt + 1);
    __syncthreads();

    f32x4 S[4];
#pragma unroll
    for (int ms = 0; ms < 4; ++ms) {
      f32x4 acc = {0.f, 0.f, 0.f, 0.f};
#pragma unroll
      for (int ks = 0; ks < 2; ++ks) {
        int row = ms * 16 + l15;
        int off = row * 64 + (((ks * 4 + quad) ^ swz) << 3);
        short8 khf = *reinterpret_cast<const short8*>(&Kh[off]);
        short8 klf = *reinterpret_cast<const short8*>(&Kl[off]);
        acc = MFMA_BF16(ql[ks], khf, acc, 0, 0, 0);
        acc = MFMA_BF16(qh[ks], klf, acc, 0, 0, 0);
        acc = MFMA_BF16(qh[ks], khf, acc, 0, 0, 0);
      }
      S[ms] = acc;
    }

    float alpha[4];
#pragma unroll
    for (int r = 0; r < 4; ++r) {
      float tm = fmaxf(fmaxf(S[0][r], S[1][r]), fmaxf(S[2][r], S[3][r]));
#pragma unroll
      for (int d = 1; d < 16; d <<= 1) tm = fmaxf(tm, __shfl_xor(tm, d, 16));
      float mn = fmaxf(M[r], tm);
      float al = __expf(M[r] - mn);
      float ts = 0.f;
      float p[4];
#pragma unroll
      for (int ms = 0; ms < 4; ++ms) { p[ms] = __expf(S[ms][r] - mn); ts += p[ms]; }
#pragma unroll
      for (int d = 1; d < 16; d <<= 1) ts += __shfl_xor(ts, d, 16);
      L[r] = L[r] * al + ts;
      M[r] = mn;
      alpha[r] = al;
      int n = 16 * w + quad * 4 + r;
#pragma unroll
      for (int ms = 0; ms < 4; ++ms) {
        int m = ms * 16 + l15;
        int off = n * 64 + (((m >> 3) ^ (n & 7)) << 3) + (m & 7);
        unsigned short h = b16(p[ms]);
        unsigned short lo = b16(p[ms] - fromb16(h));
        Ph[off] = h; Pl[off] = lo;
      }
    }
    if (l15 < 4) {
      float av = (l15 == 0) ? alpha[0] : (l15 == 1) ? alpha[1] : (l15 == 2) ? alpha[2] : alpha[3];
      sAl[16 * w + quad * 4 + l15] = av;
    }
    float av = sAl[16 * w + l15];
#pragma unroll
    for (int cs = 0; cs < 4; ++cs) {
      Oa[cs][0] *= av; Oa[cs][1] *= av; Oa[cs][2] *= av; Oa[cs][3] *= av;
    }

#pragma unroll
    for (int cs = 0; cs < 4; ++cs) {
      f32x4 acc = Oa[cs];
#pragma unroll
      for (int ks = 0; ks < 2; ++ks) {
        int vrow = cs * 16 + l15;
        int voff = vrow * 64 + (((ks * 4 + quad) ^ swz) << 3);
        short8 vhf = *reinterpret_cast<const short8*>(&Vth[voff]);
        short8 vlf = *reinterpret_cast<const short8*>(&Vtl[voff]);
        int prow = 16 * w + l15;
        int poff = prow * 64 + (((ks * 4 + quad) ^ swz) << 3);
        short8 phf = *reinterpret_cast<const short8*>(&Ph[poff]);
        short8 plf = *reinterpret_cast<const short8*>(&Pl[poff]);
        acc = MFMA_BF16(vlf, phf, acc, 0, 0, 0);
        acc = MFMA_BF16(vhf, plf, acc, 0, 0, 0);
        acc = MFMA_BF16(vhf, phf, acc, 0, 0, 0);
      }
      Oa[cs] = acc;
    }
  }

#pragma unroll
  for (int cs = 0; cs < 4; ++cs) {
#pragma unroll
    for (int r = 0; r < 4; ++r) {
      int c = cs * 16 + quad * 4 + r;
      Pg[(size_t)c * N_ + 16 * w + l15] = Oa[cs][r];
    }
  }
  if (l15 < 4) {
    float Mv = (l15 == 0) ? M[0] : (l15 == 1) ? M[1] : (l15 == 2) ? M[2] : M[3];
    float Lv = (l15 == 0) ? L[0] : (l15 == 1) ? L[1] : (l15 == 2) ? L[2] : L[3];
    int mlb = ((at * 2 + half) * 2 + b) * 4096 + qt * 64 + 16 * w + quad * 4 + l15;
    ws[ML_OFF + mlb] = Mv;
    ws[MLL_OFF + mlb] = Lv;
  }
}

// ---------------- K4: merge halves + combine ----------------
__global__ __launch_bounds__(256) void k_merge(float* __restrict__ ws,
                                               const float* __restrict__ gm_p,
                                               const float* __restrict__ al_p) {
  size_t i4 = (size_t)blockIdx.x * 256 + threadIdx.x;
  size_t i = i4 * 4;
  int n = (int)(i & 4095);
  int b = (int)(i >> 18);
  float gm = gm_p[0], al = al_p[0];
  float4 p0x = *reinterpret_cast<const float4*>(ws + XG_OFF + i);
  float4 p1x = *reinterpret_cast<const float4*>(ws + P1X_OFF + i);
  float4 p0g = *reinterpret_cast<const float4*>(ws + GG_OFF + i);
  float4 p1g = *reinterpret_cast<const float4*>(ws + P1G_OFF + i);
  float4 M0x = *reinterpret_cast<const float4*>(ws + ML_OFF  + (0 + b) * 4096 + n);
  float4 L0x = *reinterpret_cast<const float4*>(ws + MLL_OFF + (0 + b) * 4096 + n);
  float4 M1x = *reinterpret_cast<const float4*>(ws + ML_OFF  + (2 + b) * 4096 + n);
  float4 L1x = *reinterpret_cast<const float4*>(ws + MLL_OFF + (2 + b) * 4096 + n);
  float4 M0g = *reinterpret_cast<const float4*>(ws + ML_OFF  + (4 + b) * 4096 + n);
  float4 L0g = *reinterpret_cast<const float4*>(ws + MLL_OFF + (4 + b) * 4096 + n);
  float4 M1g = *reinterpret_cast<const float4*>(ws + ML_OFF  + (6 + b) * 4096 + n);
  float4 L1g = *reinterpret_cast<const float4*>(ws + MLL_OFF + (6 + b) * 4096 + n);
  const float* p0xv = (const float*)&p0x; const float* p1xv = (const float*)&p1x;
  const float* p0gv = (const float*)&p0g; const float* p1gv = (const float*)&p1g;
  const float* m0xv = (const float*)&M0x; const float* l0xv = (const float*)&L0x;
  const float* m1xv = (const float*)&M1x; const float* l1xv = (const float*)&L1x;
  const float* m0gv = (const float*)&M0g; const float* l0gv = (const float*)&L0g;
  const float* m1gv = (const float*)&M1g; const float* l1gv = (const float*)&L1g;
  float4 go, ob;
  float* gov = (float*)&go; float* obv = (float*)&ob;
#pragma unroll
  for (int l = 0; l < 4; ++l) {
    float mx = fmaxf(m0xv[l], m1xv[l]);
    float w0 = __expf(m0xv[l] - mx), w1 = __expf(m1xv[l] - mx);
    float xc = (p0xv[l] * w0 + p1xv[l] * w1) / (l0xv[l] * w0 + l1xv[l] * w1);
    float mg = fmaxf(m0gv[l], m1gv[l]);
    float v0 = __expf(m0gv[l] - mg), v1 = __expf(m1gv[l] - mg);
    float gc = (p0gv[l] * v0 + p1gv[l] * v1) / (l0gv[l] * v0 + l1gv[l] * v1);
    gov[l] = gc;
    obv[l] = gm * xc + al * gc;
  }
  *reinterpret_cast<float4*>(ws + GG_OFF + i) = go;  // GO
  *reinterpret_cast<float4*>(ws + QX_OFF + i) = ob;  // OB
}

// ---------------- K5: u = leaky(conv3x3(leaky(out), c1)), 2oc x 4px, dbuf ----------------
__global__ __launch_bounds__(256) void k_conv1(float* __restrict__ ws,
                                               const float* __restrict__ c1w,
                                               const float* __restrict__ c1b) {
  int blk = blockIdx.x;  // 256 = b*128 + og*4 + rt
  int rt = blk & 3;  blk >>= 2;
  int og = blk & 31; blk >>= 5;
  int b  = blk;
  int o0 = og * 2;
  int h0 = rt * 16;
  __shared__ __align__(16) float wl[1152];
  __shared__ __align__(16) float tile[2][18 * TRS];
  int t = threadIdx.x;
  for (int idx = t; idx < 1152; idx += 256) {
    int ch = idx / 18, rr = idx % 18;
    int k = rr >> 1, oo = rr & 1;
    wl[idx] = c1w[(size_t)(o0 + oo) * 576 + ch * 9 + k];
  }
  const float* in0 = ws + OB_OFF + (size_t)b * CN;
  int r = t >> 4, c0 = (t & 15) * 4;
  int ria = t >> 4, cia = (t & 15) * 4;
  int rib2 = 16 + (t >> 4);
  bool hasb = (t < 32);
  auto stage = [&](int ch, int ri, int ci) -> float4 {
    int hh = h0 - 1 + ri;
    float4 v = make_float4(0.f, 0.f, 0.f, 0.f);
    if (hh >= 0 && hh < 64) {
      float4 g = *reinterpret_cast<const float4*>(in0 + (size_t)ch * N_ + (size_t)hh * 64 + ci);
      v = make_float4(leaky(g.x), leaky(g.y), leaky(g.z), leaky(g.w));
    }
    return v;
  };
  float4 pfa = stage(0, ria, cia);
  float4 pfb = hasb ? stage(0, rib2, cia) : make_float4(0, 0, 0, 0);
  float acc[2][4] = {};
  for (int ch = 0; ch < 64; ++ch) {
    float* buf = tile[ch & 1];
    *reinterpret_cast<float4*>(&buf[ria * TRS + cia]) = pfa;
    if (hasb) *reinterpret_cast<float4*>(&buf[rib2 * TRS + cia]) = pfb;
    if (ch + 1 < 64) {
      pfa = stage(ch + 1, ria, cia);
      if (hasb) pfb = stage(ch + 1, rib2, cia);
    }
    __syncthreads();
#pragma unroll
    for (int ky = 0; ky < 3; ++ky) {
      int base = (r + ky) * TRS;
      float4 m = *reinterpret_cast<const float4*>(&buf[base + c0]);
      float left = (c0 > 0) ? buf[base + c0 - 1] : 0.f;
      float right = (c0 < 60) ? buf[base + c0 + 4] : 0.f;
      float t6[6] = {left, m.x, m.y, m.z, m.w, right};
#pragma unroll
      for (int kx = 0; kx < 3; ++kx) {
        float2 w2 = *reinterpret_cast<const float2*>(&wl[ch * 18 + (ky * 3 + kx) * 2]);
#pragma unroll
        for (int j = 0; j < 4; ++j) {
          float tp = t6[kx + j];
          acc[0][j] = fmaf(w2.x, tp, acc[0][j]);
          acc[1][j] = fmaf(w2.y, tp, acc[1][j]);
        }
      }
    }
  }
  size_t opix = (size_t)(h0 + r) * 64 + c0;
  float* ub = ws + UB_OFF + (size_t)b * CN;
#pragma unroll
  for (int oo = 0; oo < 2; ++oo) {
    float bb = c1b[o0 + oo];
    float4 o = make_float4(leaky(acc[oo][0] + bb), leaky(acc[oo][1] + bb),
                           leaky(acc[oo][2] + bb), leaky(acc[oo][3] + bb));
    *reinterpret_cast<float4*>(ub + (size_t)(o0 + oo) * N_ + opix) = o;
  }
}

// ---------------- K6: final, 2oc x 4px, dbuf + reg-prefetched ob ----------------
__global__ __launch_bounds__(256) void k_final(const float* __restrict__ ws,
                                               const float* __restrict__ c2w,
                                               const float* __restrict__ c2b,
                                               const float* __restrict__ scw,
                                               const float* __restrict__ scb,
                                               float* __restrict__ out) {
  int blk = blockIdx.x;  // 256 = b*128 + og*4 + rt
  int rt = blk & 3;  blk >>= 2;
  int og = blk & 31; blk >>= 5;
  int b  = blk;
  int o0 = og * 2;
  int h0 = rt * 16;
  __shared__ __align__(16) float wl[1152];
  __shared__ __align__(16) float scl[128];  // [ch][oo], oo=2
  __shared__ __align__(16) float tile[2][18 * TRS];
  int t = threadIdx.x;
  for (int idx = t; idx < 1152; idx += 256) {
    int ch = idx / 18, rr = idx % 18;
    int k = rr >> 1, oo = rr & 1;
    wl[idx] = c2w[(size_t)(o0 + oo) * 576 + ch * 9 + k];
  }
  if (t < 128) {
    int oo = t & 1, ch = t >> 1;
    scl[ch * 2 + oo] = scw[(size_t)(o0 + oo) * 64 + ch];
  }
  const float* u0 = ws + UB_OFF + (size_t)b * CN;
  const float* ob0 = ws + OB_OFF + (size_t)b * CN;
  int r = t >> 4, c0 = (t & 15) * 4;
  int ria = t >> 4, cia = (t & 15) * 4;
  int rib2 = 16 + (t >> 4);
  bool hasb = (t < 32);
  size_t mypix = (size_t)(h0 + r) * 64 + c0;
  auto stage = [&](int ch, int ri, int ci) -> float4 {
    int hh = h0 - 1 + ri;
    if (hh >= 0 && hh < 64)
      return *reinterpret_cast<const float4*>(u0 + (size_t)ch * N_ + (size_t)hh * 64 + ci);
    return make_float4(0.f, 0.f, 0.f, 0.f);
  };
  float4 pfa = stage(0, ria, cia);
  float4 pfb = hasb ? stage(0, rib2, cia) : make_float4(0, 0, 0, 0);
  float4 obc = *reinterpret_cast<const float4*>(ob0 + mypix);  // ch 0
  float acc[2][4] = {};
  float scp[2][4] = {};
  for (int ch = 0; ch < 64; ++ch) {
    float* buf = tile[ch & 1];
    *reinterpret_cast<float4*>(&buf[ria * TRS + cia]) = pfa;
    if (hasb) *reinterpret_cast<float4*>(&buf[rib2 * TRS + cia]) = pfb;
    float4 obn;
    if (ch + 1 < 64) {
      pfa = stage(ch + 1, ria, cia);
      if (hasb) pfb = stage(ch + 1, rib2, cia);
      obn = *reinterpret_cast<const float4*>(ob0 + (size_t)(ch + 1) * N_ + mypix);
    }
    __syncthreads();
#pragma unroll
    for (int ky = 0; ky < 3; ++ky) {
      int base = (r + ky) * TRS;
      float4 m = *reinterpret_cast<const float4*>(&buf[base + c0]);
      float left = (c0 > 0) ? buf[base + c0 - 1] : 0.f;
      float right = (c0 < 60) ? buf[base + c0 + 4] : 0.f;
      float t6[6] = {left, m.x, m.y, m.z, m.w, right};
#pragma unroll
      for (int kx = 0; kx < 3; ++kx) {
        float2 w2 = *reinterpret_cast<const float2*>(&wl[ch * 18 + (ky * 3 + kx) * 2]);
#pragma unroll
        for (int j = 0; j < 4; ++j) {
          float tp = t6[kx + j];
          acc[0][j] = fmaf(w2.x, tp, acc[0][j]);
          acc[1][j] = fmaf(w2.y, tp, acc[1][j]);
        }
      }
    }
    float2 s2 = *reinterpret_cast<const float2*>(&scl[ch * 2]);
    float obvv[4] = {obc.x, obc.y, obc.z, obc.w};
#pragma unroll
    for (int j = 0; j < 4; ++j) {
      scp[0][j] = fmaf(s2.x, obvv[j], scp[0][j]);
      scp[1][j] = fmaf(s2.y, obvv[j], scp[1][j]);
    }
    obc = obn;
  }
  const float* go = ws + GO_OFF + (size_t)b * CN;
  float* ob = out + (size_t)b * CN;
#pragma unroll
  for (int oo = 0; oo < 2; ++oo) {
    float c2bv = c2b[o0 + oo];
    float scbv = scb[o0 + oo];
    float4 gv = *reinterpret_cast<const float4*>(go + (size_t)(o0 + oo) * N_ + mypix);
    float4 o;
    o.x = (acc[oo][0] + c2bv) + (scp[oo][0] + scbv) * gv.x;
    o.y = (acc[oo][1] + c2bv) + (scp[oo][1] + scbv) * gv.y;
    o.z = (acc[oo][2] + c2bv) + (scp[oo][2] + scbv) * gv.z;
    o.w = (acc[oo][3] + c2bv) + (scp[oo][3] + scbv) * gv.w;
    *reinterpret_cast<float4*>(ob + (size_t)(o0 + oo) * N_ + mypix) = o;
  }
}

extern "C" void kernel_launch(void* const* d_in, const int* in_sizes, int n_in,
                              void* d_out, int out_size, void* d_ws, size_t ws_size,
                              hipStream_t stream) {
  const float* x     = (const float*)d_in[0];
  const float* guide = (const float*)d_in[1];
  const float* lin_w = (const float*)d_in[2];
  const float* lin_b = (const float*)d_in[3];
  const float* cw    = (const float*)d_in[4];
  const float* xq_w  = (const float*)d_in[5];
  const float* xq_b  = (const float*)d_in[6];
  const float* xk_w  = (const float*)d_in[7];
  const float* xk_b  = (const float*)d_in[8];
  const float* xv_w  = (const float*)d_in[9];
  const float* xv_b  = (const float*)d_in[10];
  const float* gq_w  = (const float*)d_in[11];
  const float* gq_b  = (const float*)d_in[12];
  const float* gk_w  = (const float*)d_in[13];
  const float* gk_b  = (const float*)d_in[14];
  const float* gamma = (const float*)d_in[15];
  const float* alpha = (const float*)d_in[16];
  const float* c1_w  = (const float*)d_in[17];
  const float* c1_b  = (const float*)d_in[18];
  const float* c2_w  = (const float*)d_in[19];
  const float* c2_b  = (const float*)d_in[20];
  const float* sc_w  = (const float*)d_in[21];
  const float* sc_b  = (const float*)d_in[22];
  float* out = (float*)d_out;
  float* ws = (float*)d_ws;

  k_coordconv<<<512, 256, 0, stream>>>(x, guide, lin_w, lin_b, cw, ws);
  k_proj<<<640, 256, 0, stream>>>(ws, xq_w, xq_b, xk_w, xk_b, xv_w, xv_b,
                                  gq_w, gq_b, gk_w, gk_b);
  k_attn<<<512, 256, 0, stream>>>(ws);
  k_merge<<<512, 256, 0, stream>>>(ws, gamma, alpha);
  k_conv1<<<256, 256, 0, stream>>>(ws, c1_w, c1_b);
  k_final<<<256, 256, 0, stream>>>(ws, c2_w, c2_b, sc_w, sc_b, out);
}

// Round 12
// 389.040 us; speedup vs baseline: 1.0327x; 1.0327x over previous
//
#include <hip/hip_runtime.h>
#include <hip/hip_bf16.h>

using bf16 = __hip_bfloat16;

#define DI __device__ __forceinline__

typedef __attribute__((ext_vector_type(8))) short short8;
typedef __attribute__((ext_vector_type(8))) unsigned short u16x8;
typedef __attribute__((ext_vector_type(4))) unsigned short u16x4;
typedef __attribute__((ext_vector_type(4))) float f32x4;

#define MFMA_BF16 __builtin_amdgcn_mfma_f32_16x16x32_bf16

DI float leaky(float x) { return x > 0.f ? x : 0.1f * x; }

// bf16 split helpers (RNE). x = hi + lo to ~2^-16 relative.
DI unsigned short b16(float x) {
  union { float f; unsigned u; } v; v.f = x;
  unsigned r = v.u + 0x7FFFu + ((v.u >> 16) & 1u);
  return (unsigned short)(r >> 16);
}
DI float fromb16(unsigned short h) {
  union { unsigned u; float f; } v; v.u = ((unsigned)h) << 16; return v.f;
}

// Problem constants: B=2, C=64, H=64, W=64, N=4096
// Inputs are fp32 (established R3/R4).
static constexpr int N_ = 4096;
static constexpr size_t CN = 262144;
static constexpr size_t BCN = 524288;

// ---- Workspace layout (float indices) ----
static constexpr size_t XG_OFF = 137104;
static constexpr size_t GG_OFF = XG_OFF + BCN;
static constexpr size_t QX_OFF = GG_OFF + BCN;
static constexpr size_t KX_OFF = QX_OFF + BCN;
static constexpr size_t VX_OFF = KX_OFF + BCN;
static constexpr size_t QG_OFF = VX_OFF + BCN;
static constexpr size_t KG_OFF = QG_OFF + BCN;
static constexpr size_t P1X_OFF = KG_OFF + BCN;
static constexpr size_t P1G_OFF = P1X_OFF + BCN;
static constexpr size_t ML_OFF  = P1G_OFF + BCN;
static constexpr size_t MLL_OFF = ML_OFF + 32768;
static constexpr size_t OB_OFF = QX_OFF;
static constexpr size_t UB_OFF = KX_OFF;
static constexpr size_t GO_OFF = GG_OFF;
static constexpr size_t QXH_U = QX_OFF * 2, QXL_U = QXH_U + BCN;
static constexpr size_t KXH_U = KX_OFF * 2, KXL_U = KXH_U + BCN;
static constexpr size_t VXH_U = VX_OFF * 2, VXL_U = VXH_U + BCN;
static constexpr size_t QGH_U = QG_OFF * 2, QGL_U = QGH_U + BCN;
static constexpr size_t KGH_U = KG_OFF * 2, KGL_U = KGH_U + BCN;
// Peak 19.7 MB (validated R6-R11)

// ---- conv tile constants: 16 output rows x 64 cols, 18 input rows, stride 68 ----
static constexpr int TRS = 68;

DI float4 cc_stage(const float* in, int b, int ch, int hh, int ci) {
  float4 v = make_float4(0.f, 0.f, 0.f, 0.f);
  if (hh >= 0 && hh < 64) {
    if (ch < 64) {
      v = *reinterpret_cast<const float4*>(in + ((size_t)(b * 64 + ch)) * N_ + (size_t)hh * 64 + ci);
    } else if (ch == 64) {
      v.x = (float)ci * (2.f / 63.f) - 1.f;       v.y = (float)(ci + 1) * (2.f / 63.f) - 1.f;
      v.z = (float)(ci + 2) * (2.f / 63.f) - 1.f; v.w = (float)(ci + 3) * (2.f / 63.f) - 1.f;
    } else {
      float y = (float)hh * (2.f / 63.f) - 1.f;
      v = make_float4(y, y, y, y);
    }
  }
  return v;
}

// ---------------- K1: coord-conv 3x3 + inline channel attention (2 oc/block) ----------------
__global__ __launch_bounds__(256) void k_coordconv(const float* __restrict__ x,
                                                   const float* __restrict__ g,
                                                   const float* __restrict__ lw_p,
                                                   const float* __restrict__ lb_p,
                                                   const float* __restrict__ cw,
                                                   float* __restrict__ ws) {
  int blk = blockIdx.x;  // 512 = src*256 + b*128 + og*4 + rt
  int rt = blk & 3;   blk >>= 2;
  int og = blk & 31;  blk >>= 5;
  int b  = blk & 1;   blk >>= 1;
  int src = blk;
  int o0 = og * 2;
  int h0 = rt * 16;
  const float* in = src ? g : x;
  float* outp = ws + (src ? GG_OFF : XG_OFF);
  __shared__ __align__(16) float wl[1188];          // [ch][tap][oo], oo=2
  __shared__ __align__(16) float tile[2][18 * TRS];
  __shared__ float sCA[2];
  int t = threadIdx.x;

  {
    int wv = t >> 6, lane = t & 63;
    if (wv < 2) {
      const float* chp = in + ((size_t)(b * 64 + o0 + wv)) * N_;
      float s = 0.f;
      for (int i = lane; i < N_; i += 64) s += chp[i];
#pragma unroll
      for (int d = 1; d < 64; d <<= 1) s += __shfl_xor(s, d, 64);
      if (lane == 0) {
        float p = s * (1.f / (float)N_);
        float lwv = lw_p[0], lbv = lb_p[0];
        float h = leaky(lwv * p + lbv);
        sCA[wv] = 1.f / (1.f + expf(-(lwv * h + lbv)));
      }
    }
  }

  for (int idx = t; idx < 1188; idx += 256) {
    int ch = idx / 18, rr = idx % 18;
    int k = rr >> 1, oo = rr & 1;
    wl[idx] = cw[(size_t)(o0 + oo) * 594 + ch * 9 + k];
  }
  int r = t >> 4, c0 = (t & 15) * 4;
  int ria = t >> 4, cia = (t & 15) * 4;
  int rib2 = 16 + (t >> 4);
  bool hasb = (t < 32);
  float4 pfa = cc_stage(in, b, 0, h0 - 1 + ria, cia);
  float4 pfb = hasb ? cc_stage(in, b, 0, h0 - 1 + rib2, cia) : make_float4(0, 0, 0, 0);
  float acc[2][4] = {};
  for (int ch = 0; ch < 66; ++ch) {
    float* buf = tile[ch & 1];
    *reinterpret_cast<float4*>(&buf[ria * TRS + cia]) = pfa;
    if (hasb) *reinterpret_cast<float4*>(&buf[rib2 * TRS + cia]) = pfb;
    if (ch + 1 < 66) {
      pfa = cc_stage(in, b, ch + 1, h0 - 1 + ria, cia);
      if (hasb) pfb = cc_stage(in, b, ch + 1, h0 - 1 + rib2, cia);
    }
    __syncthreads();
#pragma unroll
    for (int ky = 0; ky < 3; ++ky) {
      int base = (r + ky) * TRS;
      float4 m = *reinterpret_cast<const float4*>(&buf[base + c0]);
      float left = (c0 > 0) ? buf[base + c0 - 1] : 0.f;
      float right = (c0 < 60) ? buf[base + c0 + 4] : 0.f;
      float t6[6] = {left, m.x, m.y, m.z, m.w, right};
#pragma unroll
      for (int kx = 0; kx < 3; ++kx) {
        float2 w2 = *reinterpret_cast<const float2*>(&wl[ch * 18 + (ky * 3 + kx) * 2]);
#pragma unroll
        for (int j = 0; j < 4; ++j) {
          float tp = t6[kx + j];
          acc[0][j] = fmaf(w2.x, tp, acc[0][j]);
          acc[1][j] = fmaf(w2.y, tp, acc[1][j]);
        }
      }
    }
  }
  size_t opix = (size_t)(h0 + r) * 64 + c0;
#pragma unroll
  for (int oo = 0; oo < 2; ++oo) {
    float s = sCA[oo];
    float4 o = make_float4(acc[oo][0] * s, acc[oo][1] * s, acc[oo][2] * s, acc[oo][3] * s);
    *reinterpret_cast<float4*>(outp + ((size_t)(b * 64 + o0 + oo)) * N_ + opix) = o;
  }
}

// ---------------- K2: 1x1 projections; outputs pre-split bf16 hi/lo ----------------
__global__ __launch_bounds__(256) void k_proj(float* __restrict__ ws,
                                              const float* __restrict__ xqw, const float* __restrict__ xqb,
                                              const float* __restrict__ xkw, const float* __restrict__ xkb,
                                              const float* __restrict__ xvw, const float* __restrict__ xvb,
                                              const float* __restrict__ gqw, const float* __restrict__ gqb,
                                              const float* __restrict__ gkw, const float* __restrict__ gkb) {
  int blk = blockIdx.x;  // 5 * 2 * 64
  int pt = blk & 63; blk >>= 6;
  int b  = blk & 1;  blk >>= 1;
  int which = blk;
  size_t in_o;
  const float *wp, *bp;
  size_t hU = 0, lU = 0;
  if (which == 0)      { in_o = XG_OFF; wp = xqw; bp = xqb; hU = QXH_U; lU = QXL_U; }
  else if (which == 1) { in_o = XG_OFF; wp = xkw; bp = xkb; hU = KXH_U; lU = KXL_U; }
  else if (which == 2) { in_o = XG_OFF; wp = xvw; bp = xvb; }
  else if (which == 3) { in_o = GG_OFF; wp = gqw; bp = gqb; hU = QGH_U; lU = QGL_U; }
  else                 { in_o = GG_OFF; wp = gkw; bp = gkb; hU = KGH_U; lU = KGL_U; }

  __shared__ float tile[64 * 64];
  __shared__ float wl[64 * 65];
  __shared__ float bl[64];
  unsigned short* us = (unsigned short*)ws;
  int t = threadIdx.x;
  int pb = pt * 64;
  const float* in0 = ws + in_o + (size_t)b * CN + pb;
  for (int c0 = (t >> 6); c0 < 64; c0 += 4)
    tile[c0 * 64 + (t & 63)] = in0[(size_t)c0 * N_ + (t & 63)];
  for (int idx = t; idx < 4096; idx += 256)
    wl[(idx >> 6) * 65 + (idx & 63)] = wp[idx];
  if (t < 64) bl[t] = bp[t];
  __syncthreads();
  int o = t & 63, grp = t >> 6;
  const float* wr = &wl[o * 65];
  float acc[16];
  float bv = bl[o];
#pragma unroll
  for (int j = 0; j < 16; ++j) acc[j] = bv;
  for (int c = 0; c < 64; ++c) {
    float wv = wr[c];
    const float4* tb = reinterpret_cast<const float4*>(&tile[c * 64 + grp * 16]);
    float4 t0 = tb[0], t1 = tb[1], t2 = tb[2], t3 = tb[3];
    acc[0] = fmaf(wv, t0.x, acc[0]);   acc[1] = fmaf(wv, t0.y, acc[1]);
    acc[2] = fmaf(wv, t0.z, acc[2]);   acc[3] = fmaf(wv, t0.w, acc[3]);
    acc[4] = fmaf(wv, t1.x, acc[4]);   acc[5] = fmaf(wv, t1.y, acc[5]);
    acc[6] = fmaf(wv, t1.z, acc[6]);   acc[7] = fmaf(wv, t1.w, acc[7]);
    acc[8] = fmaf(wv, t2.x, acc[8]);   acc[9] = fmaf(wv, t2.y, acc[9]);
    acc[10] = fmaf(wv, t2.z, acc[10]); acc[11] = fmaf(wv, t2.w, acc[11]);
    acc[12] = fmaf(wv, t3.x, acc[12]); acc[13] = fmaf(wv, t3.y, acc[13]);
    acc[14] = fmaf(wv, t3.z, acc[14]); acc[15] = fmaf(wv, t3.w, acc[15]);
  }
  if (which != 2) {
#pragma unroll
    for (int j = 0; j < 16; ++j) {
      size_t idx = ((size_t)b * N_ + pb + grp * 16 + j) * 64 + o;
      unsigned short hi = b16(acc[j]);
      us[hU + idx] = hi;
      us[lU + idx] = b16(acc[j] - fromb16(hi));
    }
  } else {
    __syncthreads();
    float* ot = wl;
#pragma unroll
    for (int j = 0; j < 16; ++j) ot[o * 65 + grp * 16 + j] = acc[j];
    __syncthreads();
    int o2 = t >> 2;
#pragma unroll
    for (int e = 0; e < 4; ++e) {
      int px = (t & 3) * 16 + e * 4;
      u16x4 hv, lv;
#pragma unroll
      for (int q = 0; q < 4; ++q) {
        float v = ot[o2 * 65 + px + q];
        unsigned short hi = b16(v);
        hv[q] = hi; lv[q] = b16(v - fromb16(hi));
      }
      size_t idx = ((size_t)(b * 64 + o2)) * N_ + pb + px;
      *reinterpret_cast<u16x4*>(&us[VXH_U + idx]) = hv;
      *reinterpret_cast<u16x4*>(&us[VXL_U + idx]) = lv;
    }
  }
}

// ---------------- K3: MFMA flash attention (bf16-only P, reg-prefetch dbuf) ----------------
__global__ __launch_bounds__(256) void k_attn(float* __restrict__ ws) {
  unsigned short* us = (unsigned short*)ws;
  int blk = blockIdx.x;
  int half = blk & 1; blk >>= 1;
  int qt = blk & 63;  blk >>= 6;
  int b  = blk & 1;   blk >>= 1;
  int at = blk;
  const unsigned short* QH = us + (at ? QGH_U : QXH_U);
  const unsigned short* QL = us + (at ? QGL_U : QXL_U);
  const unsigned short* KHg = us + (at ? KGH_U : KXH_U);
  const unsigned short* KLg = us + (at ? KGL_U : KXL_U);
  const unsigned short* VHg = us + VXH_U;
  const unsigned short* VLg = us + VXL_U;
  float* Pg = ws + (at ? (half ? P1G_OFF : GG_OFF) : (half ? P1X_OFF : XG_OFF))
            + (size_t)b * CN + qt * 64;

  __shared__ unsigned short Kh[4096], Kl[4096], Vth[4096], Vtl[4096], Ph[4096];
  __shared__ float sAl[64];

  int t = threadIdx.x;
  int w = t >> 6, lane = t & 63, quad = lane >> 4, l15 = lane & 15;
  int swz = l15 & 7;

  short8 qh[2], ql[2];
  {
    size_t qbase = ((size_t)b * N_ + qt * 64 + 16 * w + l15) * 64;
#pragma unroll
    for (int ks = 0; ks < 2; ++ks) {
      qh[ks] = *reinterpret_cast<const short8*>(&QH[qbase + ks * 32 + quad * 8]);
      ql[ks] = *reinterpret_cast<const short8*>(&QL[qbase + ks * 32 + quad * 8]);
    }
  }

  u16x8 rkh[2], rkl[2], rvh[2], rvl[2];
  auto prefetch = [&](int mt) {
#pragma unroll
    for (int it = 0; it < 2; ++it) {
      int f8 = it * 256 + t;
      int r = f8 >> 3, ch = f8 & 7;
      size_t kgi = ((size_t)b * N_ + mt * 64 + r) * 64 + ch * 8;
      rkh[it] = *reinterpret_cast<const u16x8*>(&KHg[kgi]);
      rkl[it] = *reinterpret_cast<const u16x8*>(&KLg[kgi]);
      size_t vgi = ((size_t)(b * 64 + r)) * N_ + mt * 64 + ch * 8;
      rvh[it] = *reinterpret_cast<const u16x8*>(&VHg[vgi]);
      rvl[it] = *reinterpret_cast<const u16x8*>(&VLg[vgi]);
    }
  };

  f32x4 Oa[4] = {{0.f, 0.f, 0.f, 0.f}, {0.f, 0.f, 0.f, 0.f},
                 {0.f, 0.f, 0.f, 0.f}, {0.f, 0.f, 0.f, 0.f}};
  float M[4] = {-1e30f, -1e30f, -1e30f, -1e30f};
  float L[4] = {0.f, 0.f, 0.f, 0.f};

  int mt0 = half * 32, mt1 = half * 32 + 32;
  prefetch(mt0);
  for (int mt = mt0; mt < mt1; ++mt) {
    __syncthreads();
#pragma unroll
    for (int it = 0; it < 2; ++it) {
      int f8 = it * 256 + t;
      int r = f8 >> 3, ch = f8 & 7;
      int off = r * 64 + ((ch ^ (r & 7)) << 3);
      *reinterpret_cast<u16x8*>(&Kh[off]) = rkh[it];
      *reinterpret_cast<u16x8*>(&Kl[off]) = rkl[it];
      *reinterpret_cast<u16x8*>(&Vth[off]) = rvh[it];
      *reinterpret_cast<u16x8*>(&Vtl[off]) = rvl[it];
    }
    if (mt + 1 < mt1) prefetch(mt + 1);
    __syncthreads();

    f32x4 S[4];
#pragma unroll
    for (int ms = 0; ms < 4; ++ms) {
      f32x4 acc = {0.f, 0.f, 0.f, 0.f};
#pragma unroll
      for (int ks = 0; ks < 2; ++ks) {
        int row = ms * 16 + l15;
        int off = row * 64 + (((ks * 4 + quad) ^ swz) << 3);
        short8 khf = *reinterpret_cast<const short8*>(&Kh[off]);
        short8 klf = *reinterpret_cast<const short8*>(&Kl[off]);
        acc = MFMA_BF16(ql[ks], khf, acc, 0, 0, 0);
        acc = MFMA_BF16(qh[ks], klf, acc, 0, 0, 0);
        acc = MFMA_BF16(qh[ks], khf, acc, 0, 0, 0);
      }
      S[ms] = acc;
    }

    float alpha[4];
#pragma unroll
    for (int r = 0; r < 4; ++r) {
      float tm = fmaxf(fmaxf(S[0][r], S[1][r]), fmaxf(S[2][r], S[3][r]));
#pragma unroll
      for (int d = 1; d < 16; d <<= 1) tm = fmaxf(tm, __shfl_xor(tm, d, 16));
      float mn = fmaxf(M[r], tm);
      float al = __expf(M[r] - mn);
      float ts = 0.f;
      float p[4];
#pragma unroll
      for (int ms = 0; ms < 4; ++ms) { p[ms] = __expf(S[ms][r] - mn); ts += p[ms]; }
#pragma unroll
      for (int d = 1; d < 16; d <<= 1) ts += __shfl_xor(ts, d, 16);
      L[r] = L[r] * al + ts;
      M[r] = mn;
      alpha[r] = al;
      int n = 16 * w + quad * 4 + r;
#pragma unroll
      for (int ms = 0; ms < 4; ++ms) {
        int m = ms * 16 + l15;
        int off = n * 64 + (((m >> 3) ^ (n & 7)) << 3) + (m & 7);
        Ph[off] = b16(p[ms]);   // P stored hi-only (error ~2^-9, within budget)
      }
    }
    if (l15 < 4) {
      float av = (l15 == 0) ? alpha[0] : (l15 == 1) ? alpha[1] : (l15 == 2) ? alpha[2] : alpha[3];
      sAl[16 * w + quad * 4 + l15] = av;
    }
    float av = sAl[16 * w + l15];
#pragma unroll
    for (int cs = 0; cs < 4; ++cs) {
      Oa[cs][0] *= av; Oa[cs][1] *= av; Oa[cs][2] *= av; Oa[cs][3] *= av;
    }

#pragma unroll
    for (int cs = 0; cs < 4; ++cs) {
      f32x4 acc = Oa[cs];
#pragma unroll
      for (int ks = 0; ks < 2; ++ks) {
        int vrow = cs * 16 + l15;
        int voff = vrow * 64 + (((ks * 4 + quad) ^ swz) << 3);
        short8 vhf = *reinterpret_cast<const short8*>(&Vth[voff]);
        short8 vlf = *reinterpret_cast<const short8*>(&Vtl[voff]);
        int prow = 16 * w + l15;
        int poff = prow * 64 + (((ks * 4 + quad) ^ swz) << 3);
        short8 phf = *reinterpret_cast<const short8*>(&Ph[poff]);
        acc = MFMA_BF16(vlf, phf, acc, 0, 0, 0);
        acc = MFMA_BF16(vhf, phf, acc, 0, 0, 0);
      }
      Oa[cs] = acc;
    }
  }

#pragma unroll
  for (int cs = 0; cs < 4; ++cs) {
#pragma unroll
    for (int r = 0; r < 4; ++r) {
      int c = cs * 16 + quad * 4 + r;
      Pg[(size_t)c * N_ + 16 * w + l15] = Oa[cs][r];
    }
  }
  if (l15 < 4) {
    float Mv = (l15 == 0) ? M[0] : (l15 == 1) ? M[1] : (l15 == 2) ? M[2] : M[3];
    float Lv = (l15 == 0) ? L[0] : (l15 == 1) ? L[1] : (l15 == 2) ? L[2] : L[3];
    int mlb = ((at * 2 + half) * 2 + b) * 4096 + qt * 64 + 16 * w + quad * 4 + l15;
    ws[ML_OFF + mlb] = Mv;
    ws[MLL_OFF + mlb] = Lv;
  }
}

// ---------------- K4: merge halves + combine ----------------
__global__ __launch_bounds__(256) void k_merge(float* __restrict__ ws,
                                               const float* __restrict__ gm_p,
                                               const float* __restrict__ al_p) {
  size_t i4 = (size_t)blockIdx.x * 256 + threadIdx.x;
  size_t i = i4 * 4;
  int n = (int)(i & 4095);
  int b = (int)(i >> 18);
  float gm = gm_p[0], al = al_p[0];
  float4 p0x = *reinterpret_cast<const float4*>(ws + XG_OFF + i);
  float4 p1x = *reinterpret_cast<const float4*>(ws + P1X_OFF + i);
  float4 p0g = *reinterpret_cast<const float4*>(ws + GG_OFF + i);
  float4 p1g = *reinterpret_cast<const float4*>(ws + P1G_OFF + i);
  float4 M0x = *reinterpret_cast<const float4*>(ws + ML_OFF  + (0 + b) * 4096 + n);
  float4 L0x = *reinterpret_cast<const float4*>(ws + MLL_OFF + (0 + b) * 4096 + n);
  float4 M1x = *reinterpret_cast<const float4*>(ws + ML_OFF  + (2 + b) * 4096 + n);
  float4 L1x = *reinterpret_cast<const float4*>(ws + MLL_OFF + (2 + b) * 4096 + n);
  float4 M0g = *reinterpret_cast<const float4*>(ws + ML_OFF  + (4 + b) * 4096 + n);
  float4 L0g = *reinterpret_cast<const float4*>(ws + MLL_OFF + (4 + b) * 4096 + n);
  float4 M1g = *reinterpret_cast<const float4*>(ws + ML_OFF  + (6 + b) * 4096 + n);
  float4 L1g = *reinterpret_cast<const float4*>(ws + MLL_OFF + (6 + b) * 4096 + n);
  const float* p0xv = (const float*)&p0x; const float* p1xv = (const float*)&p1x;
  const float* p0gv = (const float*)&p0g; const float* p1gv = (const float*)&p1g;
  const float* m0xv = (const float*)&M0x; const float* l0xv = (const float*)&L0x;
  const float* m1xv = (const float*)&M1x; const float* l1xv = (const float*)&L1x;
  const float* m0gv = (const float*)&M0g; const float* l0gv = (const float*)&L0g;
  const float* m1gv = (const float*)&M1g; const float* l1gv = (const float*)&L1g;
  float4 go, ob;
  float* gov = (float*)&go; float* obv = (float*)&ob;
#pragma unroll
  for (int l = 0; l < 4; ++l) {
    float mx = fmaxf(m0xv[l], m1xv[l]);
    float w0 = __expf(m0xv[l] - mx), w1 = __expf(m1xv[l] - mx);
    float xc = (p0xv[l] * w0 + p1xv[l] * w1) / (l0xv[l] * w0 + l1xv[l] * w1);
    float mg = fmaxf(m0gv[l], m1gv[l]);
    float v0 = __expf(m0gv[l] - mg), v1 = __expf(m1gv[l] - mg);
    float gc = (p0gv[l] * v0 + p1gv[l] * v1) / (l0gv[l] * v0 + l1gv[l] * v1);
    gov[l] = gc;
    obv[l] = gm * xc + al * gc;
  }
  *reinterpret_cast<float4*>(ws + GG_OFF + i) = go;  // GO
  *reinterpret_cast<float4*>(ws + QX_OFF + i) = ob;  // OB
}

// ---------------- K5: u = leaky(conv3x3(leaky(out), c1)), 2oc x 4px, dbuf ----------------
__global__ __launch_bounds__(256) void k_conv1(float* __restrict__ ws,
                                               const float* __restrict__ c1w,
                                               const float* __restrict__ c1b) {
  int blk = blockIdx.x;  // 256 = b*128 + og*4 + rt
  int rt = blk & 3;  blk >>= 2;
  int og = blk & 31; blk >>= 5;
  int b  = blk;
  int o0 = og * 2;
  int h0 = rt * 16;
  __shared__ __align__(16) float wl[1152];
  __shared__ __align__(16) float tile[2][18 * TRS];
  int t = threadIdx.x;
  for (int idx = t; idx < 1152; idx += 256) {
    int ch = idx / 18, rr = idx % 18;
    int k = rr >> 1, oo = rr & 1;
    wl[idx] = c1w[(size_t)(o0 + oo) * 576 + ch * 9 + k];
  }
  const float* in0 = ws + OB_OFF + (size_t)b * CN;
  int r = t >> 4, c0 = (t & 15) * 4;
  int ria = t >> 4, cia = (t & 15) * 4;
  int rib2 = 16 + (t >> 4);
  bool hasb = (t < 32);
  auto stage = [&](int ch, int ri, int ci) -> float4 {
    int hh = h0 - 1 + ri;
    float4 v = make_float4(0.f, 0.f, 0.f, 0.f);
    if (hh >= 0 && hh < 64) {
      float4 g = *reinterpret_cast<const float4*>(in0 + (size_t)ch * N_ + (size_t)hh * 64 + ci);
      v = make_float4(leaky(g.x), leaky(g.y), leaky(g.z), leaky(g.w));
    }
    return v;
  };
  float4 pfa = stage(0, ria, cia);
  float4 pfb = hasb ? stage(0, rib2, cia) : make_float4(0, 0, 0, 0);
  float acc[2][4] = {};
  for (int ch = 0; ch < 64; ++ch) {
    float* buf = tile[ch & 1];
    *reinterpret_cast<float4*>(&buf[ria * TRS + cia]) = pfa;
    if (hasb) *reinterpret_cast<float4*>(&buf[rib2 * TRS + cia]) = pfb;
    if (ch + 1 < 64) {
      pfa = stage(ch + 1, ria, cia);
      if (hasb) pfb = stage(ch + 1, rib2, cia);
    }
    __syncthreads();
#pragma unroll
    for (int ky = 0; ky < 3; ++ky) {
      int base = (r + ky) * TRS;
      float4 m = *reinterpret_cast<const float4*>(&buf[base + c0]);
      float left = (c0 > 0) ? buf[base + c0 - 1] : 0.f;
      float right = (c0 < 60) ? buf[base + c0 + 4] : 0.f;
      float t6[6] = {left, m.x, m.y, m.z, m.w, right};
#pragma unroll
      for (int kx = 0; kx < 3; ++kx) {
        float2 w2 = *reinterpret_cast<const float2*>(&wl[ch * 18 + (ky * 3 + kx) * 2]);
#pragma unroll
        for (int j = 0; j < 4; ++j) {
          float tp = t6[kx + j];
          acc[0][j] = fmaf(w2.x, tp, acc[0][j]);
          acc[1][j] = fmaf(w2.y, tp, acc[1][j]);
        }
      }
    }
  }
  size_t opix = (size_t)(h0 + r) * 64 + c0;
  float* ub = ws + UB_OFF + (size_t)b * CN;
#pragma unroll
  for (int oo = 0; oo < 2; ++oo) {
    float bb = c1b[o0 + oo];
    float4 o = make_float4(leaky(acc[oo][0] + bb), leaky(acc[oo][1] + bb),
                           leaky(acc[oo][2] + bb), leaky(acc[oo][3] + bb));
    *reinterpret_cast<float4*>(ub + (size_t)(o0 + oo) * N_ + opix) = o;
  }
}

// ---------------- K6: final, 2oc x 4px, dbuf + reg-prefetched ob ----------------
__global__ __launch_bounds__(256) void k_final(const float* __restrict__ ws,
                                               const float* __restrict__ c2w,
                                               const float* __restrict__ c2b,
                                               const float* __restrict__ scw,
                                               const float* __restrict__ scb,
                                               float* __restrict__ out) {
  int blk = blockIdx.x;  // 256 = b*128 + og*4 + rt
  int rt = blk & 3;  blk >>= 2;
  int og = blk & 31; blk >>= 5;
  int b  = blk;
  int o0 = og * 2;
  int h0 = rt * 16;
  __shared__ __align__(16) float wl[1152];
  __shared__ __align__(16) float scl[128];  // [ch][oo], oo=2
  __shared__ __align__(16) float tile[2][18 * TRS];
  int t = threadIdx.x;
  for (int idx = t; idx < 1152; idx += 256) {
    int ch = idx / 18, rr = idx % 18;
    int k = rr >> 1, oo = rr & 1;
    wl[idx] = c2w[(size_t)(o0 + oo) * 576 + ch * 9 + k];
  }
  if (t < 128) {
    int oo = t & 1, ch = t >> 1;
    scl[ch * 2 + oo] = scw[(size_t)(o0 + oo) * 64 + ch];
  }
  const float* u0 = ws + UB_OFF + (size_t)b * CN;
  const float* ob0 = ws + OB_OFF + (size_t)b * CN;
  int r = t >> 4, c0 = (t & 15) * 4;
  int ria = t >> 4, cia = (t & 15) * 4;
  int rib2 = 16 + (t >> 4);
  bool hasb = (t < 32);
  size_t mypix = (size_t)(h0 + r) * 64 + c0;
  auto stage = [&](int ch, int ri, int ci) -> float4 {
    int hh = h0 - 1 + ri;
    if (hh >= 0 && hh < 64)
      return *reinterpret_cast<const float4*>(u0 + (size_t)ch * N_ + (size_t)hh * 64 + ci);
    return make_float4(0.f, 0.f, 0.f, 0.f);
  };
  float4 pfa = stage(0, ria, cia);
  float4 pfb = hasb ? stage(0, rib2, cia) : make_float4(0, 0, 0, 0);
  float4 obc = *reinterpret_cast<const float4*>(ob0 + mypix);  // ch 0
  float acc[2][4] = {};
  float scp[2][4] = {};
  for (int ch = 0; ch < 64; ++ch) {
    float* buf = tile[ch & 1];
    *reinterpret_cast<float4*>(&buf[ria * TRS + cia]) = pfa;
    if (hasb) *reinterpret_cast<float4*>(&buf[rib2 * TRS + cia]) = pfb;
    float4 obn;
    if (ch + 1 < 64) {
      pfa = stage(ch + 1, ria, cia);
      if (hasb) pfb = stage(ch + 1, rib2, cia);
      obn = *reinterpret_cast<const float4*>(ob0 + (size_t)(ch + 1) * N_ + mypix);
    }
    __syncthreads();
#pragma unroll
    for (int ky = 0; ky < 3; ++ky) {
      int base = (r + ky) * TRS;
      float4 m = *reinterpret_cast<const float4*>(&buf[base + c0]);
      float left = (c0 > 0) ? buf[base + c0 - 1] : 0.f;
      float right = (c0 < 60) ? buf[base + c0 + 4] : 0.f;
      float t6[6] = {left, m.x, m.y, m.z, m.w, right};
#pragma unroll
      for (int kx = 0; kx < 3; ++kx) {
        float2 w2 = *reinterpret_cast<const float2*>(&wl[ch * 18 + (ky * 3 + kx) * 2]);
#pragma unroll
        for (int j = 0; j < 4; ++j) {
          float tp = t6[kx + j];
          acc[0][j] = fmaf(w2.x, tp, acc[0][j]);
          acc[1][j] = fmaf(w2.y, tp, acc[1][j]);
        }
      }
    }
    float2 s2 = *reinterpret_cast<const float2*>(&scl[ch * 2]);
    float obvv[4] = {obc.x, obc.y, obc.z, obc.w};
#pragma unroll
    for (int j = 0; j < 4; ++j) {
      scp[0][j] = fmaf(s2.x, obvv[j], scp[0][j]);
      scp[1][j] = fmaf(s2.y, obvv[j], scp[1][j]);
    }
    obc = obn;
  }
  const float* go = ws + GO_OFF + (size_t)b * CN;
  float* ob = out + (size_t)b * CN;
#pragma unroll
  for (int oo = 0; oo < 2; ++oo) {
    float c2bv = c2b[o0 + oo];
    float scbv = scb[o0 + oo];
    float4 gv = *reinterpret_cast<const float4*>(go + (size_t)(o0 + oo) * N_ + mypix);
    float4 o;
    o.x = (acc[oo][0] + c2bv) + (scp[oo][0] + scbv) * gv.x;
    o.y = (acc[oo][1] + c2bv) + (scp[oo][1] + scbv) * gv.y;
    o.z = (acc[oo][2] + c2bv) + (scp[oo][2] + scbv) * gv.z;
    o.w = (acc[oo][3] + c2bv) + (scp[oo][3] + scbv) * gv.w;
    *reinterpret_cast<float4*>(ob + (size_t)(o0 + oo) * N_ + mypix) = o;
  }
}

extern "C" void kernel_launch(void* const* d_in, const int* in_sizes, int n_in,
                              void* d_out, int out_size, void* d_ws, size_t ws_size,
                              hipStream_t stream) {
  const float* x     = (const float*)d_in[0];
  const float* guide = (const float*)d_in[1];
  const float* lin_w = (const float*)d_in[2];
  const float* lin_b = (const float*)d_in[3];
  const float* cw    = (const float*)d_in[4];
  const float* xq_w  = (const float*)d_in[5];
  const float* xq_b  = (const float*)d_in[6];
  const float* xk_w  = (const float*)d_in[7];
  const float* xk_b  = (const float*)d_in[8];
  const float* xv_w  = (const float*)d_in[9];
  const float* xv_b  = (const float*)d_in[10];
  const float* gq_w  = (const float*)d_in[11];
  const float* gq_b  = (const float*)d_in[12];
  const float* gk_w  = (const float*)d_in[13];
  const float* gk_b  = (const float*)d_in[14];
  const float* gamma = (const float*)d_in[15];
  const float* alpha = (const float*)d_in[16];
  const float* c1_w  = (const float*)d_in[17];
  const float* c1_b  = (const float*)d_in[18];
  const float* c2_w  = (const float*)d_in[19];
  const float* c2_b  = (const float*)d_in[20];
  const float* sc_w  = (const float*)d_in[21];
  const float* sc_b  = (const float*)d_in[22];
  float* out = (float*)d_out;
  float* ws = (float*)d_ws;

  k_coordconv<<<512, 256, 0, stream>>>(x, guide, lin_w, lin_b, cw, ws);
  k_proj<<<640, 256, 0, stream>>>(ws, xq_w, xq_b, xk_w, xk_b, xv_w, xv_b,
                                  gq_w, gq_b, gk_w, gk_b);
  k_attn<<<512, 256, 0, stream>>>(ws);
  k_merge<<<512, 256, 0, stream>>>(ws, gamma, alpha);
  k_conv1<<<256, 256, 0, stream>>>(ws, c1_w, c1_b);
  k_final<<<256, 256, 0, stream>>>(ws, c2_w, c2_b, sc_w, sc_b, out);
}

// Round 14
// 386.395 us; speedup vs baseline: 1.0397x; 1.0068x over previous
//
#include <hip/hip_runtime.h>
#include <hip/hip_bf16.h>

using bf16 = __hip_bfloat16;

#define DI __device__ __forceinline__

typedef __attribute__((ext_vector_type(8))) short short8;
typedef __attribute__((ext_vector_type(8))) unsigned short u16x8;
typedef __attribute__((ext_vector_type(4))) unsigned short u16x4;
typedef __attribute__((ext_vector_type(4))) float f32x4;

#define MFMA_BF16 __builtin_amdgcn_mfma_f32_16x16x32_bf16

DI float leaky(float x) { return x > 0.f ? x : 0.1f * x; }

// bf16 split helpers (RNE). x = hi + lo to ~2^-16 relative.
DI unsigned short b16(float x) {
  union { float f; unsigned u; } v; v.f = x;
  unsigned r = v.u + 0x7FFFu + ((v.u >> 16) & 1u);
  return (unsigned short)(r >> 16);
}
DI float fromb16(unsigned short h) {
  union { unsigned u; float f; } v; v.u = ((unsigned)h) << 16; return v.f;
}

// Problem constants: B=2, C=64, H=64, W=64, N=4096. Inputs fp32 (R3/R4).
// NOTE R13: hipLaunchCooperativeKernel fails silently under the harness's
// graph capture (zero-output signature) — do NOT use cooperative launch here.
static constexpr int N_ = 4096;
static constexpr size_t CN = 262144;
static constexpr size_t BCN = 524288;

// ---- Workspace layout (float indices) ----
static constexpr size_t XG_OFF = 137104;
static constexpr size_t GG_OFF = XG_OFF + BCN;
static constexpr size_t QX_OFF = GG_OFF + BCN;
static constexpr size_t KX_OFF = QX_OFF + BCN;
static constexpr size_t VX_OFF = KX_OFF + BCN;
static constexpr size_t QG_OFF = VX_OFF + BCN;
static constexpr size_t KG_OFF = QG_OFF + BCN;
static constexpr size_t P1X_OFF = KG_OFF + BCN;
static constexpr size_t P1G_OFF = P1X_OFF + BCN;
static constexpr size_t ML_OFF  = P1G_OFF + BCN;
static constexpr size_t MLL_OFF = ML_OFF + 32768;
static constexpr size_t OB_OFF = QX_OFF;
static constexpr size_t UB_OFF = KX_OFF;
static constexpr size_t GO_OFF = GG_OFF;
static constexpr size_t QXH_U = QX_OFF * 2, QXL_U = QXH_U + BCN;
static constexpr size_t KXH_U = KX_OFF * 2, KXL_U = KXH_U + BCN;
static constexpr size_t VXH_U = VX_OFF * 2, VXL_U = VXH_U + BCN;
static constexpr size_t QGH_U = QG_OFF * 2, QGL_U = QGH_U + BCN;
static constexpr size_t KGH_U = KG_OFF * 2, KGL_U = KGH_U + BCN;
// Peak 19.7 MB (validated R6-R12)

static constexpr int TRS = 68;

DI float4 cc_stage(const float* in, int b, int ch, int hh, int ci) {
  float4 v = make_float4(0.f, 0.f, 0.f, 0.f);
  if (hh >= 0 && hh < 64) {
    if (ch < 64) {
      v = *reinterpret_cast<const float4*>(in + ((size_t)(b * 64 + ch)) * N_ + (size_t)hh * 64 + ci);
    } else if (ch == 64) {
      v.x = (float)ci * (2.f / 63.f) - 1.f;       v.y = (float)(ci + 1) * (2.f / 63.f) - 1.f;
      v.z = (float)(ci + 2) * (2.f / 63.f) - 1.f; v.w = (float)(ci + 3) * (2.f / 63.f) - 1.f;
    } else {
      float y = (float)hh * (2.f / 63.f) - 1.f;
      v = make_float4(y, y, y, y);
    }
  }
  return v;
}

// ---------------- K1: coord-conv 3x3 + inline channel attention (2 oc/block) ----------------
__global__ __launch_bounds__(256) void k_coordconv(const float* __restrict__ x,
                                                   const float* __restrict__ g,
                                                   const float* __restrict__ lw_p,
                                                   const float* __restrict__ lb_p,
                                                   const float* __restrict__ cw,
                                                   float* __restrict__ ws) {
  int blk = blockIdx.x;  // 512 = src*256 + b*128 + og*4 + rt
  int rt = blk & 3;   blk >>= 2;
  int og = blk & 31;  blk >>= 5;
  int b  = blk & 1;   blk >>= 1;
  int src = blk;
  int o0 = og * 2;
  int h0 = rt * 16;
  const float* in = src ? g : x;
  float* outp = ws + (src ? GG_OFF : XG_OFF);
  __shared__ __align__(16) float wl[1188];          // [ch][tap][oo], oo=2
  __shared__ __align__(16) float tile[2][18 * TRS];
  __shared__ float sCA[2];
  int t = threadIdx.x;

  {
    int wv = t >> 6, lane = t & 63;
    if (wv < 2) {
      const float* chp = in + ((size_t)(b * 64 + o0 + wv)) * N_;
      float s = 0.f;
      for (int i = lane; i < N_; i += 64) s += chp[i];
#pragma unroll
      for (int d = 1; d < 64; d <<= 1) s += __shfl_xor(s, d, 64);
      if (lane == 0) {
        float p = s * (1.f / (float)N_);
        float lwv = lw_p[0], lbv = lb_p[0];
        float h = leaky(lwv * p + lbv);
        sCA[wv] = 1.f / (1.f + expf(-(lwv * h + lbv)));
      }
    }
  }

  for (int idx = t; idx < 1188; idx += 256) {
    int ch = idx / 18, rr = idx % 18;
    int k = rr >> 1, oo = rr & 1;
    wl[idx] = cw[(size_t)(o0 + oo) * 594 + ch * 9 + k];
  }
  int r = t >> 4, c0 = (t & 15) * 4;
  int ria = t >> 4, cia = (t & 15) * 4;
  int rib2 = 16 + (t >> 4);
  bool hasb = (t < 32);
  float4 pfa = cc_stage(in, b, 0, h0 - 1 + ria, cia);
  float4 pfb = hasb ? cc_stage(in, b, 0, h0 - 1 + rib2, cia) : make_float4(0, 0, 0, 0);
  float acc[2][4] = {};
  for (int ch = 0; ch < 66; ++ch) {
    float* buf = tile[ch & 1];
    *reinterpret_cast<float4*>(&buf[ria * TRS + cia]) = pfa;
    if (hasb) *reinterpret_cast<float4*>(&buf[rib2 * TRS + cia]) = pfb;
    if (ch + 1 < 66) {
      pfa = cc_stage(in, b, ch + 1, h0 - 1 + ria, cia);
      if (hasb) pfb = cc_stage(in, b, ch + 1, h0 - 1 + rib2, cia);
    }
    __syncthreads();
#pragma unroll
    for (int ky = 0; ky < 3; ++ky) {
      int base = (r + ky) * TRS;
      float4 m = *reinterpret_cast<const float4*>(&buf[base + c0]);
      float left = (c0 > 0) ? buf[base + c0 - 1] : 0.f;
      float right = (c0 < 60) ? buf[base + c0 + 4] : 0.f;
      float t6[6] = {left, m.x, m.y, m.z, m.w, right};
#pragma unroll
      for (int kx = 0; kx < 3; ++kx) {
        float2 w2 = *reinterpret_cast<const float2*>(&wl[ch * 18 + (ky * 3 + kx) * 2]);
#pragma unroll
        for (int j = 0; j < 4; ++j) {
          float tp = t6[kx + j];
          acc[0][j] = fmaf(w2.x, tp, acc[0][j]);
          acc[1][j] = fmaf(w2.y, tp, acc[1][j]);
        }
      }
    }
  }
  size_t opix = (size_t)(h0 + r) * 64 + c0;
#pragma unroll
  for (int oo = 0; oo < 2; ++oo) {
    float s = sCA[oo];
    float4 o = make_float4(acc[oo][0] * s, acc[oo][1] * s, acc[oo][2] * s, acc[oo][3] * s);
    *reinterpret_cast<float4*>(outp + ((size_t)(b * 64 + o0 + oo)) * N_ + opix) = o;
  }
}

// ---------------- K2: 1x1 projections; outputs pre-split bf16 hi/lo ----------------
__global__ __launch_bounds__(256) void k_proj(float* __restrict__ ws,
                                              const float* __restrict__ xqw, const float* __restrict__ xqb,
                                              const float* __restrict__ xkw, const float* __restrict__ xkb,
                                              const float* __restrict__ xvw, const float* __restrict__ xvb,
                                              const float* __restrict__ gqw, const float* __restrict__ gqb,
                                              const float* __restrict__ gkw, const float* __restrict__ gkb) {
  int blk = blockIdx.x;  // 5 * 2 * 64
  int pt = blk & 63; blk >>= 6;
  int b  = blk & 1;  blk >>= 1;
  int which = blk;
  size_t in_o;
  const float *wp, *bp;
  size_t hU = 0, lU = 0;
  if (which == 0)      { in_o = XG_OFF; wp = xqw; bp = xqb; hU = QXH_U; lU = QXL_U; }
  else if (which == 1) { in_o = XG_OFF; wp = xkw; bp = xkb; hU = KXH_U; lU = KXL_U; }
  else if (which == 2) { in_o = XG_OFF; wp = xvw; bp = xvb; }
  else if (which == 3) { in_o = GG_OFF; wp = gqw; bp = gqb; hU = QGH_U; lU = QGL_U; }
  else                 { in_o = GG_OFF; wp = gkw; bp = gkb; hU = KGH_U; lU = KGL_U; }

  __shared__ float tile[64 * 64];
  __shared__ float wl[64 * 65];
  __shared__ float bl[64];
  unsigned short* us = (unsigned short*)ws;
  int t = threadIdx.x;
  int pb = pt * 64;
  const float* in0 = ws + in_o + (size_t)b * CN + pb;
  for (int c0 = (t >> 6); c0 < 64; c0 += 4)
    tile[c0 * 64 + (t & 63)] = in0[(size_t)c0 * N_ + (t & 63)];
  for (int idx = t; idx < 4096; idx += 256)
    wl[(idx >> 6) * 65 + (idx & 63)] = wp[idx];
  if (t < 64) bl[t] = bp[t];
  __syncthreads();
  int o = t & 63, grp = t >> 6;
  const float* wr = &wl[o * 65];
  float acc[16];
  float bv = bl[o];
#pragma unroll
  for (int j = 0; j < 16; ++j) acc[j] = bv;
  for (int c = 0; c < 64; ++c) {
    float wv = wr[c];
    const float4* tb = reinterpret_cast<const float4*>(&tile[c * 64 + grp * 16]);
    float4 t0 = tb[0], t1 = tb[1], t2 = tb[2], t3 = tb[3];
    acc[0] = fmaf(wv, t0.x, acc[0]);   acc[1] = fmaf(wv, t0.y, acc[1]);
    acc[2] = fmaf(wv, t0.z, acc[2]);   acc[3] = fmaf(wv, t0.w, acc[3]);
    acc[4] = fmaf(wv, t1.x, acc[4]);   acc[5] = fmaf(wv, t1.y, acc[5]);
    acc[6] = fmaf(wv, t1.z, acc[6]);   acc[7] = fmaf(wv, t1.w, acc[7]);
    acc[8] = fmaf(wv, t2.x, acc[8]);   acc[9] = fmaf(wv, t2.y, acc[9]);
    acc[10] = fmaf(wv, t2.z, acc[10]); acc[11] = fmaf(wv, t2.w, acc[11]);
    acc[12] = fmaf(wv, t3.x, acc[12]); acc[13] = fmaf(wv, t3.y, acc[13]);
    acc[14] = fmaf(wv, t3.z, acc[14]); acc[15] = fmaf(wv, t3.w, acc[15]);
  }
  if (which != 2) {
#pragma unroll
    for (int j = 0; j < 16; ++j) {
      size_t idx = ((size_t)b * N_ + pb + grp * 16 + j) * 64 + o;
      unsigned short hi = b16(acc[j]);
      us[hU + idx] = hi;
      us[lU + idx] = b16(acc[j] - fromb16(hi));
    }
  } else {
    __syncthreads();
    float* ot = wl;
#pragma unroll
    for (int j = 0; j < 16; ++j) ot[o * 65 + grp * 16 + j] = acc[j];
    __syncthreads();
    int o2 = t >> 2;
#pragma unroll
    for (int e = 0; e < 4; ++e) {
      int px = (t & 3) * 16 + e * 4;
      u16x4 hv, lv;
#pragma unroll
      for (int q = 0; q < 4; ++q) {
        float v = ot[o2 * 65 + px + q];
        unsigned short hi = b16(v);
        hv[q] = hi; lv[q] = b16(v - fromb16(hi));
      }
      size_t idx = ((size_t)(b * 64 + o2)) * N_ + pb + px;
      *reinterpret_cast<u16x4*>(&us[VXH_U + idx]) = hv;
      *reinterpret_cast<u16x4*>(&us[VXL_U + idx]) = lv;
    }
  }
}

// ---------------- K3: MFMA flash attention (LDS double-buffered K/V, 1 barrier/tile) ----------------
__global__ __launch_bounds__(256) void k_attn(float* __restrict__ ws) {
  unsigned short* us = (unsigned short*)ws;
  int blk = blockIdx.x;
  int half = blk & 1; blk >>= 1;
  int qt = blk & 63;  blk >>= 6;
  int b  = blk & 1;   blk >>= 1;
  int at = blk;
  const unsigned short* QH = us + (at ? QGH_U : QXH_U);
  const unsigned short* QL = us + (at ? QGL_U : QXL_U);
  const unsigned short* KHg = us + (at ? KGH_U : KXH_U);
  const unsigned short* KLg = us + (at ? KGL_U : KXL_U);
  const unsigned short* VHg = us + VXH_U;
  const unsigned short* VLg = us + VXL_U;
  float* Pg = ws + (at ? (half ? P1G_OFF : GG_OFF) : (half ? P1X_OFF : XG_OFF))
            + (size_t)b * CN + qt * 64;

  // double-buffered K/V (74 KB total; 2 blocks/CU still fits: 148 <= 160 KB)
  __shared__ unsigned short Kh[2][4096], Kl[2][4096], Vth[2][4096], Vtl[2][4096], Ph[4096];
  __shared__ float sAl[64];

  int t = threadIdx.x;
  int w = t >> 6, lane = t & 63, quad = lane >> 4, l15 = lane & 15;
  int swz = l15 & 7;

  short8 qh[2], ql[2];
  {
    size_t qbase = ((size_t)b * N_ + qt * 64 + 16 * w + l15) * 64;
#pragma unroll
    for (int ks = 0; ks < 2; ++ks) {
      qh[ks] = *reinterpret_cast<const short8*>(&QH[qbase + ks * 32 + quad * 8]);
      ql[ks] = *reinterpret_cast<const short8*>(&QL[qbase + ks * 32 + quad * 8]);
    }
  }

  u16x8 rkh[2], rkl[2], rvh[2], rvl[2];
  auto prefetch = [&](int mt) {
#pragma unroll
    for (int it = 0; it < 2; ++it) {
      int f8 = it * 256 + t;
      int r = f8 >> 3, ch = f8 & 7;
      size_t kgi = ((size_t)b * N_ + mt * 64 + r) * 64 + ch * 8;
      rkh[it] = *reinterpret_cast<const u16x8*>(&KHg[kgi]);
      rkl[it] = *reinterpret_cast<const u16x8*>(&KLg[kgi]);
      size_t vgi = ((size_t)(b * 64 + r)) * N_ + mt * 64 + ch * 8;
      rvh[it] = *reinterpret_cast<const u16x8*>(&VHg[vgi]);
      rvl[it] = *reinterpret_cast<const u16x8*>(&VLg[vgi]);
    }
  };
  auto writebuf = [&](int par) {
#pragma unroll
    for (int it = 0; it < 2; ++it) {
      int f8 = it * 256 + t;
      int r = f8 >> 3, ch = f8 & 7;
      int off = r * 64 + ((ch ^ (r & 7)) << 3);
      *reinterpret_cast<u16x8*>(&Kh[par][off]) = rkh[it];
      *reinterpret_cast<u16x8*>(&Kl[par][off]) = rkl[it];
      *reinterpret_cast<u16x8*>(&Vth[par][off]) = rvh[it];
      *reinterpret_cast<u16x8*>(&Vtl[par][off]) = rvl[it];
    }
  };

  f32x4 Oa[4] = {{0.f, 0.f, 0.f, 0.f}, {0.f, 0.f, 0.f, 0.f},
                 {0.f, 0.f, 0.f, 0.f}, {0.f, 0.f, 0.f, 0.f}};
  float M[4] = {-1e30f, -1e30f, -1e30f, -1e30f};
  float L[4] = {0.f, 0.f, 0.f, 0.f};

  int mt0 = half * 32, mt1 = half * 32 + 32;
  prefetch(mt0);
  writebuf(0);
  __syncthreads();
  for (int mt = mt0; mt < mt1; ++mt) {
    int pb = (mt - mt0) & 1;
    if (mt + 1 < mt1) prefetch(mt + 1);  // global latency overlaps tile compute

    f32x4 S[4];
#pragma unroll
    for (int ms = 0; ms < 4; ++ms) {
      f32x4 acc = {0.f, 0.f, 0.f, 0.f};
#pragma unroll
      for (int ks = 0; ks < 2; ++ks) {
        int row = ms * 16 + l15;
        int off = row * 64 + (((ks * 4 + quad) ^ swz) << 3);
        short8 khf = *reinterpret_cast<const short8*>(&Kh[pb][off]);
        short8 klf = *reinterpret_cast<const short8*>(&Kl[pb][off]);
        acc = MFMA_BF16(ql[ks], khf, acc, 0, 0, 0);
        acc = MFMA_BF16(qh[ks], klf, acc, 0, 0, 0);
        acc = MFMA_BF16(qh[ks], khf, acc, 0, 0, 0);
      }
      S[ms] = acc;
    }

    float alpha[4];
#pragma unroll
    for (int r = 0; r < 4; ++r) {
      float tm = fmaxf(fmaxf(S[0][r], S[1][r]), fmaxf(S[2][r], S[3][r]));
#pragma unroll
      for (int d = 1; d < 16; d <<= 1) tm = fmaxf(tm, __shfl_xor(tm, d, 16));
      float mn = fmaxf(M[r], tm);
      float al = __expf(M[r] - mn);
      float ts = 0.f;
      float p[4];
#pragma unroll
      for (int ms = 0; ms < 4; ++ms) { p[ms] = __expf(S[ms][r] - mn); ts += p[ms]; }
#pragma unroll
      for (int d = 1; d < 16; d <<= 1) ts += __shfl_xor(ts, d, 16);
      L[r] = L[r] * al + ts;
      M[r] = mn;
      alpha[r] = al;
      int n = 16 * w + quad * 4 + r;
#pragma unroll
      for (int ms = 0; ms < 4; ++ms) {
        int m = ms * 16 + l15;
        int off = n * 64 + (((m >> 3) ^ (n & 7)) << 3) + (m & 7);
        Ph[off] = b16(p[ms]);   // P hi-only (validated R12); wave-private rows -> no barrier
      }
    }
    if (l15 < 4) {
      float av = (l15 == 0) ? alpha[0] : (l15 == 1) ? alpha[1] : (l15 == 2) ? alpha[2] : alpha[3];
      sAl[16 * w + quad * 4 + l15] = av;
    }
    float av = sAl[16 * w + l15];
#pragma unroll
    for (int cs = 0; cs < 4; ++cs) {
      Oa[cs][0] *= av; Oa[cs][1] *= av; Oa[cs][2] *= av; Oa[cs][3] *= av;
    }

#pragma unroll
    for (int cs = 0; cs < 4; ++cs) {
      f32x4 acc = Oa[cs];
#pragma unroll
      for (int ks = 0; ks < 2; ++ks) {
        int vrow = cs * 16 + l15;
        int voff = vrow * 64 + (((ks * 4 + quad) ^ swz) << 3);
        short8 vhf = *reinterpret_cast<const short8*>(&Vth[pb][voff]);
        short8 vlf = *reinterpret_cast<const short8*>(&Vtl[pb][voff]);
        int prow = 16 * w + l15;
        int poff = prow * 64 + (((ks * 4 + quad) ^ swz) << 3);
        short8 phf = *reinterpret_cast<const short8*>(&Ph[poff]);
        acc = MFMA_BF16(vlf, phf, acc, 0, 0, 0);
        acc = MFMA_BF16(vhf, phf, acc, 0, 0, 0);
      }
      Oa[cs] = acc;
    }

    if (mt + 1 < mt1) writebuf(pb ^ 1);  // target buffer last read at mt-1, fenced by prior barrier
    __syncthreads();
  }

#pragma unroll
  for (int cs = 0; cs < 4; ++cs) {
#pragma unroll
    for (int r = 0; r < 4; ++r) {
      int c = cs * 16 + quad * 4 + r;
      Pg[(size_t)c * N_ + 16 * w + l15] = Oa[cs][r];
    }
  }
  if (l15 < 4) {
    float Mv = (l15 == 0) ? M[0] : (l15 == 1) ? M[1] : (l15 == 2) ? M[2] : M[3];
    float Lv = (l15 == 0) ? L[0] : (l15 == 1) ? L[1] : (l15 == 2) ? L[2] : L[3];
    int mlb = ((at * 2 + half) * 2 + b) * 4096 + qt * 64 + 16 * w + quad * 4 + l15;
    ws[ML_OFF + mlb] = Mv;
    ws[MLL_OFF + mlb] = Lv;
  }
}

// ---------------- K4: merge halves + combine ----------------
__global__ __launch_bounds__(256) void k_merge(float* __restrict__ ws,
                                               const float* __restrict__ gm_p,
                                               const float* __restrict__ al_p) {
  size_t i4 = (size_t)blockIdx.x * 256 + threadIdx.x;
  size_t i = i4 * 4;
  int n = (int)(i & 4095);
  int b = (int)(i >> 18);
  float gm = gm_p[0], al = al_p[0];
  float4 p0x = *reinterpret_cast<const float4*>(ws + XG_OFF + i);
  float4 p1x = *reinterpret_cast<const float4*>(ws + P1X_OFF + i);
  float4 p0g = *reinterpret_cast<const float4*>(ws + GG_OFF + i);
  float4 p1g = *reinterpret_cast<const float4*>(ws + P1G_OFF + i);
  float4 M0x = *reinterpret_cast<const float4*>(ws + ML_OFF  + (0 + b) * 4096 + n);
  float4 L0x = *reinterpret_cast<const float4*>(ws + MLL_OFF + (0 + b) * 4096 + n);
  float4 M1x = *reinterpret_cast<const float4*>(ws + ML_OFF  + (2 + b) * 4096 + n);
  float4 L1x = *reinterpret_cast<const float4*>(ws + MLL_OFF + (2 + b) * 4096 + n);
  float4 M0g = *reinterpret_cast<const float4*>(ws + ML_OFF  + (4 + b) * 4096 + n);
  float4 L0g = *reinterpret_cast<const float4*>(ws + MLL_OFF + (4 + b) * 4096 + n);
  float4 M1g = *reinterpret_cast<const float4*>(ws + ML_OFF  + (6 + b) * 4096 + n);
  float4 L1g = *reinterpret_cast<const float4*>(ws + MLL_OFF + (6 + b) * 4096 + n);
  const float* p0xv = (const float*)&p0x; const float* p1xv = (const float*)&p1x;
  const float* p0gv = (const float*)&p0g; const float* p1gv = (const float*)&p1g;
  const float* m0xv = (const float*)&M0x; const float* l0xv = (const float*)&L0x;
  const float* m1xv = (const float*)&M1x; const float* l1xv = (const float*)&L1x;
  const float* m0gv = (const float*)&M0g; const float* l0gv = (const float*)&L0g;
  const float* m1gv = (const float*)&M1g; const float* l1gv = (const float*)&L1g;
  float4 go, ob;
  float* gov = (float*)&go; float* obv = (float*)&ob;
#pragma unroll
  for (int l = 0; l < 4; ++l) {
    float mx = fmaxf(m0xv[l], m1xv[l]);
    float w0 = __expf(m0xv[l] - mx), w1 = __expf(m1xv[l] - mx);
    float xc = (p0xv[l] * w0 + p1xv[l] * w1) / (l0xv[l] * w0 + l1xv[l] * w1);
    float mg = fmaxf(m0gv[l], m1gv[l]);
    float v0 = __expf(m0gv[l] - mg), v1 = __expf(m1gv[l] - mg);
    float gc = (p0gv[l] * v0 + p1gv[l] * v1) / (l0gv[l] * v0 + l1gv[l] * v1);
    gov[l] = gc;
    obv[l] = gm * xc + al * gc;
  }
  *reinterpret_cast<float4*>(ws + GG_OFF + i) = go;  // GO
  *reinterpret_cast<float4*>(ws + QX_OFF + i) = ob;  // OB
}

// ---------------- K5: u = leaky(conv3x3(leaky(out), c1)), 2oc x 4px, dbuf ----------------
__global__ __launch_bounds__(256) void k_conv1(float* __restrict__ ws,
                                               const float* __restrict__ c1w,
                                               const float* __restrict__ c1b) {
  int blk = blockIdx.x;  // 256 = b*128 + og*4 + rt
  int rt = blk & 3;  blk >>= 2;
  int og = blk & 31; blk >>= 5;
  int b  = blk;
  int o0 = og * 2;
  int h0 = rt * 16;
  __shared__ __align__(16) float wl[1152];
  __shared__ __align__(16) float tile[2][18 * TRS];
  int t = threadIdx.x;
  for (int idx = t; idx < 1152; idx += 256) {
    int ch = idx / 18, rr = idx % 18;
    int k = rr >> 1, oo = rr & 1;
    wl[idx] = c1w[(size_t)(o0 + oo) * 576 + ch * 9 + k];
  }
  const float* in0 = ws + OB_OFF + (size_t)b * CN;
  int r = t >> 4, c0 = (t & 15) * 4;
  int ria = t >> 4, cia = (t & 15) * 4;
  int rib2 = 16 + (t >> 4);
  bool hasb = (t < 32);
  auto stage = [&](int ch, int ri, int ci) -> float4 {
    int hh = h0 - 1 + ri;
    float4 v = make_float4(0.f, 0.f, 0.f, 0.f);
    if (hh >= 0 && hh < 64) {
      float4 g = *reinterpret_cast<const float4*>(in0 + (size_t)ch * N_ + (size_t)hh * 64 + ci);
      v = make_float4(leaky(g.x), leaky(g.y), leaky(g.z), leaky(g.w));
    }
    return v;
  };
  float4 pfa = stage(0, ria, cia);
  float4 pfb = hasb ? stage(0, rib2, cia) : make_float4(0, 0, 0, 0);
  float acc[2][4] = {};
  for (int ch = 0; ch < 64; ++ch) {
    float* buf = tile[ch & 1];
    *reinterpret_cast<float4*>(&buf[ria * TRS + cia]) = pfa;
    if (hasb) *reinterpret_cast<float4*>(&buf[rib2 * TRS + cia]) = pfb;
    if (ch + 1 < 64) {
      pfa = stage(ch + 1, ria, cia);
      if (hasb) pfb = stage(ch + 1, rib2, cia);
    }
    __syncthreads();
#pragma unroll
    for (int ky = 0; ky < 3; ++ky) {
      int base = (r + ky) * TRS;
      float4 m = *reinterpret_cast<const float4*>(&buf[base + c0]);
      float left = (c0 > 0) ? buf[base + c0 - 1] : 0.f;
      float right = (c0 < 60) ? buf[base + c0 + 4] : 0.f;
      float t6[6] = {left, m.x, m.y, m.z, m.w, right};
#pragma unroll
      for (int kx = 0; kx < 3; ++kx) {
        float2 w2 = *reinterpret_cast<const float2*>(&wl[ch * 18 + (ky * 3 + kx) * 2]);
#pragma unroll
        for (int j = 0; j < 4; ++j) {
          float tp = t6[kx + j];
          acc[0][j] = fmaf(w2.x, tp, acc[0][j]);
          acc[1][j] = fmaf(w2.y, tp, acc[1][j]);
        }
      }
    }
  }
  size_t opix = (size_t)(h0 + r) * 64 + c0;
  float* ub = ws + UB_OFF + (size_t)b * CN;
#pragma unroll
  for (int oo = 0; oo < 2; ++oo) {
    float bb = c1b[o0 + oo];
    float4 o = make_float4(leaky(acc[oo][0] + bb), leaky(acc[oo][1] + bb),
                           leaky(acc[oo][2] + bb), leaky(acc[oo][3] + bb));
    *reinterpret_cast<float4*>(ub + (size_t)(o0 + oo) * N_ + opix) = o;
  }
}

// ---------------- K6: final, 2oc x 4px, dbuf + reg-prefetched ob ----------------
__global__ __launch_bounds__(256) void k_final(const float* __restrict__ ws,
                                               const float* __restrict__ c2w,
                                               const float* __restrict__ c2b,
                                               const float* __restrict__ scw,
                                               const float* __restrict__ scb,
                                               float* __restrict__ out) {
  int blk = blockIdx.x;  // 256 = b*128 + og*4 + rt
  int rt = blk & 3;  blk >>= 2;
  int og = blk & 31; blk >>= 5;
  int b  = blk;
  int o0 = og * 2;
  int h0 = rt * 16;
  __shared__ __align__(16) float wl[1152];
  __shared__ __align__(16) float scl[128];  // [ch][oo], oo=2
  __shared__ __align__(16) float tile[2][18 * TRS];
  int t = threadIdx.x;
  for (int idx = t; idx < 1152; idx += 256) {
    int ch = idx / 18, rr = idx % 18;
    int k = rr >> 1, oo = rr & 1;
    wl[idx] = c2w[(size_t)(o0 + oo) * 576 + ch * 9 + k];
  }
  if (t < 128) {
    int oo = t & 1, ch = t >> 1;
    scl[ch * 2 + oo] = scw[(size_t)(o0 + oo) * 64 + ch];
  }
  const float* u0 = ws + UB_OFF + (size_t)b * CN;
  const float* ob0 = ws + OB_OFF + (size_t)b * CN;
  int r = t >> 4, c0 = (t & 15) * 4;
  int ria = t >> 4, cia = (t & 15) * 4;
  int rib2 = 16 + (t >> 4);
  bool hasb = (t < 32);
  size_t mypix = (size_t)(h0 + r) * 64 + c0;
  auto stage = [&](int ch, int ri, int ci) -> float4 {
    int hh = h0 - 1 + ri;
    if (hh >= 0 && hh < 64)
      return *reinterpret_cast<const float4*>(u0 + (size_t)ch * N_ + (size_t)hh * 64 + ci);
    return make_float4(0.f, 0.f, 0.f, 0.f);
  };
  float4 pfa = stage(0, ria, cia);
  float4 pfb = hasb ? stage(0, rib2, cia) : make_float4(0, 0, 0, 0);
  float4 obc = *reinterpret_cast<const float4*>(ob0 + mypix);  // ch 0
  float acc[2][4] = {};
  float scp[2][4] = {};
  for (int ch = 0; ch < 64; ++ch) {
    float* buf = tile[ch & 1];
    *reinterpret_cast<float4*>(&buf[ria * TRS + cia]) = pfa;
    if (hasb) *reinterpret_cast<float4*>(&buf[rib2 * TRS + cia]) = pfb;
    float4 obn;
    if (ch + 1 < 64) {
      pfa = stage(ch + 1, ria, cia);
      if (hasb) pfb = stage(ch + 1, rib2, cia);
      obn = *reinterpret_cast<const float4*>(ob0 + (size_t)(ch + 1) * N_ + mypix);
    }
    __syncthreads();
#pragma unroll
    for (int ky = 0; ky < 3; ++ky) {
      int base = (r + ky) * TRS;
      float4 m = *reinterpret_cast<const float4*>(&buf[base + c0]);
      float left = (c0 > 0) ? buf[base + c0 - 1] : 0.f;
      float right = (c0 < 60) ? buf[base + c0 + 4] : 0.f;
      float t6[6] = {left, m.x, m.y, m.z, m.w, right};
#pragma unroll
      for (int kx = 0; kx < 3; ++kx) {
        float2 w2 = *reinterpret_cast<const float2*>(&wl[ch * 18 + (ky * 3 + kx) * 2]);
#pragma unroll
        for (int j = 0; j < 4; ++j) {
          float tp = t6[kx + j];
          acc[0][j] = fmaf(w2.x, tp, acc[0][j]);
          acc[1][j] = fmaf(w2.y, tp, acc[1][j]);
        }
      }
    }
    float2 s2 = *reinterpret_cast<const float2*>(&scl[ch * 2]);
    float obvv[4] = {obc.x, obc.y, obc.z, obc.w};
#pragma unroll
    for (int j = 0; j < 4; ++j) {
      scp[0][j] = fmaf(s2.x, obvv[j], scp[0][j]);
      scp[1][j] = fmaf(s2.y, obvv[j], scp[1][j]);
    }
    obc = obn;
  }
  const float* go = ws + GO_OFF + (size_t)b * CN;
  float* ob = out + (size_t)b * CN;
#pragma unroll
  for (int oo = 0; oo < 2; ++oo) {
    float c2bv = c2b[o0 + oo];
    float scbv = scb[o0 + oo];
    float4 gv = *reinterpret_cast<const float4*>(go + (size_t)(o0 + oo) * N_ + mypix);
    float4 o;
    o.x = (acc[oo][0] + c2bv) + (scp[oo][0] + scbv) * gv.x;
    o.y = (acc[oo][1] + c2bv) + (scp[oo][1] + scbv) * gv.y;
    o.z = (acc[oo][2] + c2bv) + (scp[oo][2] + scbv) * gv.z;
    o.w = (acc[oo][3] + c2bv) + (scp[oo][3] + scbv) * gv.w;
    *reinterpret_cast<float4*>(ob + (size_t)(o0 + oo) * N_ + mypix) = o;
  }
}

extern "C" void kernel_launch(void* const* d_in, const int* in_sizes, int n_in,
                              void* d_out, int out_size, void* d_ws, size_t ws_size,
                              hipStream_t stream) {
  const float* x     = (const float*)d_in[0];
  const float* guide = (const float*)d_in[1];
  const float* lin_w = (const float*)d_in[2];
  const float* lin_b = (const float*)d_in[3];
  const float* cw    = (const float*)d_in[4];
  const float* xq_w  = (const float*)d_in[5];
  const float* xq_b  = (const float*)d_in[6];
  const float* xk_w  = (const float*)d_in[7];
  const float* xk_b  = (const float*)d_in[8];
  const float* xv_w  = (const float*)d_in[9];
  const float* xv_b  = (const float*)d_in[10];
  const float* gq_w  = (const float*)d_in[11];
  const float* gq_b  = (const float*)d_in[12];
  const float* gk_w  = (const float*)d_in[13];
  const float* gk_b  = (const float*)d_in[14];
  const float* gamma = (const float*)d_in[15];
  const float* alpha = (const float*)d_in[16];
  const float* c1_w  = (const float*)d_in[17];
  const float* c1_b  = (const float*)d_in[18];
  const float* c2_w  = (const float*)d_in[19];
  const float* c2_b  = (const float*)d_in[20];
  const float* sc_w  = (const float*)d_in[21];
  const float* sc_b  = (const float*)d_in[22];
  float* out = (float*)d_out;
  float* ws = (float*)d_ws;

  k_coordconv<<<512, 256, 0, stream>>>(x, guide, lin_w, lin_b, cw, ws);
  k_proj<<<640, 256, 0, stream>>>(ws, xq_w, xq_b, xk_w, xk_b, xv_w, xv_b,
                                  gq_w, gq_b, gk_w, gk_b);
  k_attn<<<512, 256, 0, stream>>>(ws);
  k_merge<<<512, 256, 0, stream>>>(ws, gamma, alpha);
  k_conv1<<<256, 256, 0, stream>>>(ws, c1_w, c1_b);
  k_final<<<256, 256, 0, stream>>>(ws, c2_w, c2_b, sc_w, sc_b, out);
}

// Round 15
// 375.783 us; speedup vs baseline: 1.0691x; 1.0282x over previous
//
#include <hip/hip_runtime.h>
#include <hip/hip_bf16.h>

using bf16 = __hip_bfloat16;

#define DI __device__ __forceinline__

typedef __attribute__((ext_vector_type(8))) short short8;
typedef __attribute__((ext_vector_type(8))) unsigned short u16x8;
typedef __attribute__((ext_vector_type(4))) unsigned short u16x4;
typedef __attribute__((ext_vector_type(4))) float f32x4;

#define MFMA_BF16 __builtin_amdgcn_mfma_f32_16x16x32_bf16

DI float leaky(float x) { return x > 0.f ? x : 0.1f * x; }

// bf16 split helpers (RNE). x = hi + lo to ~2^-16 relative.
DI unsigned short b16(float x) {
  union { float f; unsigned u; } v; v.f = x;
  unsigned r = v.u + 0x7FFFu + ((v.u >> 16) & 1u);
  return (unsigned short)(r >> 16);
}
DI float fromb16(unsigned short h) {
  union { unsigned u; float f; } v; v.u = ((unsigned)h) << 16; return v.f;
}

// Problem constants: B=2, C=64, H=64, W=64, N=4096. Inputs fp32 (R3/R4).
// NOTE R13: hipLaunchCooperativeKernel fails silently under graph capture here.
// Precision ladder (validated): Q/K split bf16 (required — logits feed exp),
// P hi-only (R12: absmax 9.8e-4), V hi-only in PV (this round).
static constexpr int N_ = 4096;
static constexpr size_t CN = 262144;
static constexpr size_t BCN = 524288;

// ---- Workspace layout (float indices) ----
static constexpr size_t XG_OFF = 137104;
static constexpr size_t GG_OFF = XG_OFF + BCN;
static constexpr size_t QX_OFF = GG_OFF + BCN;
static constexpr size_t KX_OFF = QX_OFF + BCN;
static constexpr size_t VX_OFF = KX_OFF + BCN;
static constexpr size_t QG_OFF = VX_OFF + BCN;
static constexpr size_t KG_OFF = QG_OFF + BCN;
static constexpr size_t P1X_OFF = KG_OFF + BCN;
static constexpr size_t P1G_OFF = P1X_OFF + BCN;
static constexpr size_t ML_OFF  = P1G_OFF + BCN;
static constexpr size_t MLL_OFF = ML_OFF + 32768;
static constexpr size_t OB_OFF = QX_OFF;
static constexpr size_t UB_OFF = KX_OFF;
static constexpr size_t GO_OFF = GG_OFF;
static constexpr size_t QXH_U = QX_OFF * 2, QXL_U = QXH_U + BCN;
static constexpr size_t KXH_U = KX_OFF * 2, KXL_U = KXH_U + BCN;
static constexpr size_t VXH_U = VX_OFF * 2;
static constexpr size_t QGH_U = QG_OFF * 2, QGL_U = QGH_U + BCN;
static constexpr size_t KGH_U = KG_OFF * 2, KGL_U = KGH_U + BCN;
// Peak 19.7 MB (validated R6-R14)

static constexpr int TRS = 68;

DI float4 cc_stage(const float* in, int b, int ch, int hh, int ci) {
  float4 v = make_float4(0.f, 0.f, 0.f, 0.f);
  if (hh >= 0 && hh < 64) {
    if (ch < 64) {
      v = *reinterpret_cast<const float4*>(in + ((size_t)(b * 64 + ch)) * N_ + (size_t)hh * 64 + ci);
    } else if (ch == 64) {
      v.x = (float)ci * (2.f / 63.f) - 1.f;       v.y = (float)(ci + 1) * (2.f / 63.f) - 1.f;
      v.z = (float)(ci + 2) * (2.f / 63.f) - 1.f; v.w = (float)(ci + 3) * (2.f / 63.f) - 1.f;
    } else {
      float y = (float)hh * (2.f / 63.f) - 1.f;
      v = make_float4(y, y, y, y);
    }
  }
  return v;
}

// ---------------- K1: coord-conv 3x3 + inline channel attention (2 oc/block) ----------------
__global__ __launch_bounds__(256) void k_coordconv(const float* __restrict__ x,
                                                   const float* __restrict__ g,
                                                   const float* __restrict__ lw_p,
                                                   const float* __restrict__ lb_p,
                                                   const float* __restrict__ cw,
                                                   float* __restrict__ ws) {
  int blk = blockIdx.x;  // 512 = src*256 + b*128 + og*4 + rt
  int rt = blk & 3;   blk >>= 2;
  int og = blk & 31;  blk >>= 5;
  int b  = blk & 1;   blk >>= 1;
  int src = blk;
  int o0 = og * 2;
  int h0 = rt * 16;
  const float* in = src ? g : x;
  float* outp = ws + (src ? GG_OFF : XG_OFF);
  __shared__ __align__(16) float wl[1188];          // [ch][tap][oo], oo=2
  __shared__ __align__(16) float tile[2][18 * TRS];
  __shared__ float sCA[2];
  int t = threadIdx.x;

  {
    int wv = t >> 6, lane = t & 63;
    if (wv < 2) {
      const float* chp = in + ((size_t)(b * 64 + o0 + wv)) * N_;
      float s = 0.f;
      for (int i = lane; i < N_; i += 64) s += chp[i];
#pragma unroll
      for (int d = 1; d < 64; d <<= 1) s += __shfl_xor(s, d, 64);
      if (lane == 0) {
        float p = s * (1.f / (float)N_);
        float lwv = lw_p[0], lbv = lb_p[0];
        float h = leaky(lwv * p + lbv);
        sCA[wv] = 1.f / (1.f + expf(-(lwv * h + lbv)));
      }
    }
  }

  for (int idx = t; idx < 1188; idx += 256) {
    int ch = idx / 18, rr = idx % 18;
    int k = rr >> 1, oo = rr & 1;
    wl[idx] = cw[(size_t)(o0 + oo) * 594 + ch * 9 + k];
  }
  int r = t >> 4, c0 = (t & 15) * 4;
  int ria = t >> 4, cia = (t & 15) * 4;
  int rib2 = 16 + (t >> 4);
  bool hasb = (t < 32);
  float4 pfa = cc_stage(in, b, 0, h0 - 1 + ria, cia);
  float4 pfb = hasb ? cc_stage(in, b, 0, h0 - 1 + rib2, cia) : make_float4(0, 0, 0, 0);
  float acc[2][4] = {};
  for (int ch = 0; ch < 66; ++ch) {
    float* buf = tile[ch & 1];
    *reinterpret_cast<float4*>(&buf[ria * TRS + cia]) = pfa;
    if (hasb) *reinterpret_cast<float4*>(&buf[rib2 * TRS + cia]) = pfb;
    if (ch + 1 < 66) {
      pfa = cc_stage(in, b, ch + 1, h0 - 1 + ria, cia);
      if (hasb) pfb = cc_stage(in, b, ch + 1, h0 - 1 + rib2, cia);
    }
    __syncthreads();
#pragma unroll
    for (int ky = 0; ky < 3; ++ky) {
      int base = (r + ky) * TRS;
      float4 m = *reinterpret_cast<const float4*>(&buf[base + c0]);
      float left = (c0 > 0) ? buf[base + c0 - 1] : 0.f;
      float right = (c0 < 60) ? buf[base + c0 + 4] : 0.f;
      float t6[6] = {left, m.x, m.y, m.z, m.w, right};
#pragma unroll
      for (int kx = 0; kx < 3; ++kx) {
        float2 w2 = *reinterpret_cast<const float2*>(&wl[ch * 18 + (ky * 3 + kx) * 2]);
#pragma unroll
        for (int j = 0; j < 4; ++j) {
          float tp = t6[kx + j];
          acc[0][j] = fmaf(w2.x, tp, acc[0][j]);
          acc[1][j] = fmaf(w2.y, tp, acc[1][j]);
        }
      }
    }
  }
  size_t opix = (size_t)(h0 + r) * 64 + c0;
#pragma unroll
  for (int oo = 0; oo < 2; ++oo) {
    float s = sCA[oo];
    float4 o = make_float4(acc[oo][0] * s, acc[oo][1] * s, acc[oo][2] * s, acc[oo][3] * s);
    *reinterpret_cast<float4*>(outp + ((size_t)(b * 64 + o0 + oo)) * N_ + opix) = o;
  }
}

// ---------------- K2: 1x1 projections; Q/K pre-split hi/lo, V hi-only transposed ----------------
__global__ __launch_bounds__(256) void k_proj(float* __restrict__ ws,
                                              const float* __restrict__ xqw, const float* __restrict__ xqb,
                                              const float* __restrict__ xkw, const float* __restrict__ xkb,
                                              const float* __restrict__ xvw, const float* __restrict__ xvb,
                                              const float* __restrict__ gqw, const float* __restrict__ gqb,
                                              const float* __restrict__ gkw, const float* __restrict__ gkb) {
  int blk = blockIdx.x;  // 5 * 2 * 64
  int pt = blk & 63; blk >>= 6;
  int b  = blk & 1;  blk >>= 1;
  int which = blk;
  size_t in_o;
  const float *wp, *bp;
  size_t hU = 0, lU = 0;
  if (which == 0)      { in_o = XG_OFF; wp = xqw; bp = xqb; hU = QXH_U; lU = QXL_U; }
  else if (which == 1) { in_o = XG_OFF; wp = xkw; bp = xkb; hU = KXH_U; lU = KXL_U; }
  else if (which == 2) { in_o = XG_OFF; wp = xvw; bp = xvb; }
  else if (which == 3) { in_o = GG_OFF; wp = gqw; bp = gqb; hU = QGH_U; lU = QGL_U; }
  else                 { in_o = GG_OFF; wp = gkw; bp = gkb; hU = KGH_U; lU = KGL_U; }

  __shared__ float tile[64 * 64];
  __shared__ float wl[64 * 65];
  __shared__ float bl[64];
  unsigned short* us = (unsigned short*)ws;
  int t = threadIdx.x;
  int pb = pt * 64;
  const float* in0 = ws + in_o + (size_t)b * CN + pb;
  for (int c0 = (t >> 6); c0 < 64; c0 += 4)
    tile[c0 * 64 + (t & 63)] = in0[(size_t)c0 * N_ + (t & 63)];
  for (int idx = t; idx < 4096; idx += 256)
    wl[(idx >> 6) * 65 + (idx & 63)] = wp[idx];
  if (t < 64) bl[t] = bp[t];
  __syncthreads();
  int o = t & 63, grp = t >> 6;
  const float* wr = &wl[o * 65];
  float acc[16];
  float bv = bl[o];
#pragma unroll
  for (int j = 0; j < 16; ++j) acc[j] = bv;
  for (int c = 0; c < 64; ++c) {
    float wv = wr[c];
    const float4* tb = reinterpret_cast<const float4*>(&tile[c * 64 + grp * 16]);
    float4 t0 = tb[0], t1 = tb[1], t2 = tb[2], t3 = tb[3];
    acc[0] = fmaf(wv, t0.x, acc[0]);   acc[1] = fmaf(wv, t0.y, acc[1]);
    acc[2] = fmaf(wv, t0.z, acc[2]);   acc[3] = fmaf(wv, t0.w, acc[3]);
    acc[4] = fmaf(wv, t1.x, acc[4]);   acc[5] = fmaf(wv, t1.y, acc[5]);
    acc[6] = fmaf(wv, t1.z, acc[6]);   acc[7] = fmaf(wv, t1.w, acc[7]);
    acc[8] = fmaf(wv, t2.x, acc[8]);   acc[9] = fmaf(wv, t2.y, acc[9]);
    acc[10] = fmaf(wv, t2.z, acc[10]); acc[11] = fmaf(wv, t2.w, acc[11]);
    acc[12] = fmaf(wv, t3.x, acc[12]); acc[13] = fmaf(wv, t3.y, acc[13]);
    acc[14] = fmaf(wv, t3.z, acc[14]); acc[15] = fmaf(wv, t3.w, acc[15]);
  }
  if (which != 2) {
#pragma unroll
    for (int j = 0; j < 16; ++j) {
      size_t idx = ((size_t)b * N_ + pb + grp * 16 + j) * 64 + o;
      unsigned short hi = b16(acc[j]);
      us[hU + idx] = hi;
      us[lU + idx] = b16(acc[j] - fromb16(hi));
    }
  } else {
    __syncthreads();
    float* ot = wl;
#pragma unroll
    for (int j = 0; j < 16; ++j) ot[o * 65 + grp * 16 + j] = acc[j];
    __syncthreads();
    int o2 = t >> 2;
#pragma unroll
    for (int e = 0; e < 4; ++e) {
      int px = (t & 3) * 16 + e * 4;
      u16x4 hv;
#pragma unroll
      for (int q = 0; q < 4; ++q) hv[q] = b16(ot[o2 * 65 + px + q]);
      size_t idx = ((size_t)(b * 64 + o2)) * N_ + pb + px;
      *reinterpret_cast<u16x4*>(&us[VXH_U + idx]) = hv;
    }
  }
}

// ---------------- K3: MFMA flash attention (dbuf K/V-hi, V hi-only PV) ----------------
__global__ __launch_bounds__(256) void k_attn(float* __restrict__ ws) {
  unsigned short* us = (unsigned short*)ws;
  int blk = blockIdx.x;
  int half = blk & 1; blk >>= 1;
  int qt = blk & 63;  blk >>= 6;
  int b  = blk & 1;   blk >>= 1;
  int at = blk;
  const unsigned short* QH = us + (at ? QGH_U : QXH_U);
  const unsigned short* QL = us + (at ? QGL_U : QXL_U);
  const unsigned short* KHg = us + (at ? KGH_U : KXH_U);
  const unsigned short* KLg = us + (at ? KGL_U : KXL_U);
  const unsigned short* VHg = us + VXH_U;
  float* Pg = ws + (at ? (half ? P1G_OFF : GG_OFF) : (half ? P1X_OFF : XG_OFF))
            + (size_t)b * CN + qt * 64;

  __shared__ unsigned short Kh[2][4096], Kl[2][4096], Vth[2][4096], Ph[4096];
  __shared__ float sAl[64];

  int t = threadIdx.x;
  int w = t >> 6, lane = t & 63, quad = lane >> 4, l15 = lane & 15;
  int swz = l15 & 7;

  short8 qh[2], ql[2];
  {
    size_t qbase = ((size_t)b * N_ + qt * 64 + 16 * w + l15) * 64;
#pragma unroll
    for (int ks = 0; ks < 2; ++ks) {
      qh[ks] = *reinterpret_cast<const short8*>(&QH[qbase + ks * 32 + quad * 8]);
      ql[ks] = *reinterpret_cast<const short8*>(&QL[qbase + ks * 32 + quad * 8]);
    }
  }

  u16x8 rkh[2], rkl[2], rvh[2];
  auto prefetch = [&](int mt) {
#pragma unroll
    for (int it = 0; it < 2; ++it) {
      int f8 = it * 256 + t;
      int r = f8 >> 3, ch = f8 & 7;
      size_t kgi = ((size_t)b * N_ + mt * 64 + r) * 64 + ch * 8;
      rkh[it] = *reinterpret_cast<const u16x8*>(&KHg[kgi]);
      rkl[it] = *reinterpret_cast<const u16x8*>(&KLg[kgi]);
      size_t vgi = ((size_t)(b * 64 + r)) * N_ + mt * 64 + ch * 8;
      rvh[it] = *reinterpret_cast<const u16x8*>(&VHg[vgi]);
    }
  };
  auto writebuf = [&](int par) {
#pragma unroll
    for (int it = 0; it < 2; ++it) {
      int f8 = it * 256 + t;
      int r = f8 >> 3, ch = f8 & 7;
      int off = r * 64 + ((ch ^ (r & 7)) << 3);
      *reinterpret_cast<u16x8*>(&Kh[par][off]) = rkh[it];
      *reinterpret_cast<u16x8*>(&Kl[par][off]) = rkl[it];
      *reinterpret_cast<u16x8*>(&Vth[par][off]) = rvh[it];
    }
  };

  f32x4 Oa[4] = {{0.f, 0.f, 0.f, 0.f}, {0.f, 0.f, 0.f, 0.f},
                 {0.f, 0.f, 0.f, 0.f}, {0.f, 0.f, 0.f, 0.f}};
  float M[4] = {-1e30f, -1e30f, -1e30f, -1e30f};
  float L[4] = {0.f, 0.f, 0.f, 0.f};

  int mt0 = half * 32, mt1 = half * 32 + 32;
  prefetch(mt0);
  writebuf(0);
  __syncthreads();
  for (int mt = mt0; mt < mt1; ++mt) {
    int pb = (mt - mt0) & 1;
    if (mt + 1 < mt1) prefetch(mt + 1);  // global latency overlaps tile compute

    f32x4 S[4];
#pragma unroll
    for (int ms = 0; ms < 4; ++ms) {
      f32x4 acc = {0.f, 0.f, 0.f, 0.f};
#pragma unroll
      for (int ks = 0; ks < 2; ++ks) {
        int row = ms * 16 + l15;
        int off = row * 64 + (((ks * 4 + quad) ^ swz) << 3);
        short8 khf = *reinterpret_cast<const short8*>(&Kh[pb][off]);
        short8 klf = *reinterpret_cast<const short8*>(&Kl[pb][off]);
        acc = MFMA_BF16(ql[ks], khf, acc, 0, 0, 0);
        acc = MFMA_BF16(qh[ks], klf, acc, 0, 0, 0);
        acc = MFMA_BF16(qh[ks], khf, acc, 0, 0, 0);
      }
      S[ms] = acc;
    }

    float alpha[4];
#pragma unroll
    for (int r = 0; r < 4; ++r) {
      float tm = fmaxf(fmaxf(S[0][r], S[1][r]), fmaxf(S[2][r], S[3][r]));
#pragma unroll
      for (int d = 1; d < 16; d <<= 1) tm = fmaxf(tm, __shfl_xor(tm, d, 16));
      float mn = fmaxf(M[r], tm);
      float al = __expf(M[r] - mn);
      float ts = 0.f;
      float p[4];
#pragma unroll
      for (int ms = 0; ms < 4; ++ms) { p[ms] = __expf(S[ms][r] - mn); ts += p[ms]; }
#pragma unroll
      for (int d = 1; d < 16; d <<= 1) ts += __shfl_xor(ts, d, 16);
      L[r] = L[r] * al + ts;
      M[r] = mn;
      alpha[r] = al;
      int n = 16 * w + quad * 4 + r;
#pragma unroll
      for (int ms = 0; ms < 4; ++ms) {
        int m = ms * 16 + l15;
        int off = n * 64 + (((m >> 3) ^ (n & 7)) << 3) + (m & 7);
        Ph[off] = b16(p[ms]);   // P hi-only; wave-private rows -> no barrier needed
      }
    }
    if (l15 < 4) {
      float av = (l15 == 0) ? alpha[0] : (l15 == 1) ? alpha[1] : (l15 == 2) ? alpha[2] : alpha[3];
      sAl[16 * w + quad * 4 + l15] = av;
    }
    float av = sAl[16 * w + l15];
#pragma unroll
    for (int cs = 0; cs < 4; ++cs) {
      Oa[cs][0] *= av; Oa[cs][1] *= av; Oa[cs][2] *= av; Oa[cs][3] *= av;
    }

    // O^T += V^T P^T, V hi-only: 8 MFMAs, 10 ds_reads per tile (phf hoisted)
#pragma unroll
    for (int ks = 0; ks < 2; ++ks) {
      int prow = 16 * w + l15;
      int poff = prow * 64 + (((ks * 4 + quad) ^ swz) << 3);
      short8 phf = *reinterpret_cast<const short8*>(&Ph[poff]);
#pragma unroll
      for (int cs = 0; cs < 4; ++cs) {
        int vrow = cs * 16 + l15;
        int voff = vrow * 64 + (((ks * 4 + quad) ^ swz) << 3);
        short8 vhf = *reinterpret_cast<const short8*>(&Vth[pb][voff]);
        Oa[cs] = MFMA_BF16(vhf, phf, Oa[cs], 0, 0, 0);
      }
    }

    if (mt + 1 < mt1) writebuf(pb ^ 1);  // fenced by previous iteration's barrier
    __syncthreads();
  }

#pragma unroll
  for (int cs = 0; cs < 4; ++cs) {
#pragma unroll
    for (int r = 0; r < 4; ++r) {
      int c = cs * 16 + quad * 4 + r;
      Pg[(size_t)c * N_ + 16 * w + l15] = Oa[cs][r];
    }
  }
  if (l15 < 4) {
    float Mv = (l15 == 0) ? M[0] : (l15 == 1) ? M[1] : (l15 == 2) ? M[2] : M[3];
    float Lv = (l15 == 0) ? L[0] : (l15 == 1) ? L[1] : (l15 == 2) ? L[2] : L[3];
    int mlb = ((at * 2 + half) * 2 + b) * 4096 + qt * 64 + 16 * w + quad * 4 + l15;
    ws[ML_OFF + mlb] = Mv;
    ws[MLL_OFF + mlb] = Lv;
  }
}

// ---------------- K4: merge halves + combine ----------------
__global__ __launch_bounds__(256) void k_merge(float* __restrict__ ws,
                                               const float* __restrict__ gm_p,
                                               const float* __restrict__ al_p) {
  size_t i4 = (size_t)blockIdx.x * 256 + threadIdx.x;
  size_t i = i4 * 4;
  int n = (int)(i & 4095);
  int b = (int)(i >> 18);
  float gm = gm_p[0], al = al_p[0];
  float4 p0x = *reinterpret_cast<const float4*>(ws + XG_OFF + i);
  float4 p1x = *reinterpret_cast<const float4*>(ws + P1X_OFF + i);
  float4 p0g = *reinterpret_cast<const float4*>(ws + GG_OFF + i);
  float4 p1g = *reinterpret_cast<const float4*>(ws + P1G_OFF + i);
  float4 M0x = *reinterpret_cast<const float4*>(ws + ML_OFF  + (0 + b) * 4096 + n);
  float4 L0x = *reinterpret_cast<const float4*>(ws + MLL_OFF + (0 + b) * 4096 + n);
  float4 M1x = *reinterpret_cast<const float4*>(ws + ML_OFF  + (2 + b) * 4096 + n);
  float4 L1x = *reinterpret_cast<const float4*>(ws + MLL_OFF + (2 + b) * 4096 + n);
  float4 M0g = *reinterpret_cast<const float4*>(ws + ML_OFF  + (4 + b) * 4096 + n);
  float4 L0g = *reinterpret_cast<const float4*>(ws + MLL_OFF + (4 + b) * 4096 + n);
  float4 M1g = *reinterpret_cast<const float4*>(ws + ML_OFF  + (6 + b) * 4096 + n);
  float4 L1g = *reinterpret_cast<const float4*>(ws + MLL_OFF + (6 + b) * 4096 + n);
  const float* p0xv = (const float*)&p0x; const float* p1xv = (const float*)&p1x;
  const float* p0gv = (const float*)&p0g; const float* p1gv = (const float*)&p1g;
  const float* m0xv = (const float*)&M0x; const float* l0xv = (const float*)&L0x;
  const float* m1xv = (const float*)&M1x; const float* l1xv = (const float*)&L1x;
  const float* m0gv = (const float*)&M0g; const float* l0gv = (const float*)&L0g;
  const float* m1gv = (const float*)&M1g; const float* l1gv = (const float*)&L1g;
  float4 go, ob;
  float* gov = (float*)&go; float* obv = (float*)&ob;
#pragma unroll
  for (int l = 0; l < 4; ++l) {
    float mx = fmaxf(m0xv[l], m1xv[l]);
    float w0 = __expf(m0xv[l] - mx), w1 = __expf(m1xv[l] - mx);
    float xc = (p0xv[l] * w0 + p1xv[l] * w1) / (l0xv[l] * w0 + l1xv[l] * w1);
    float mg = fmaxf(m0gv[l], m1gv[l]);
    float v0 = __expf(m0gv[l] - mg), v1 = __expf(m1gv[l] - mg);
    float gc = (p0gv[l] * v0 + p1gv[l] * v1) / (l0gv[l] * v0 + l1gv[l] * v1);
    gov[l] = gc;
    obv[l] = gm * xc + al * gc;
  }
  *reinterpret_cast<float4*>(ws + GG_OFF + i) = go;  // GO
  *reinterpret_cast<float4*>(ws + QX_OFF + i) = ob;  // OB
}

// ---------------- K5: u = leaky(conv3x3(leaky(out), c1)), 2oc x 4px, dbuf ----------------
__global__ __launch_bounds__(256) void k_conv1(float* __restrict__ ws,
                                               const float* __restrict__ c1w,
                                               const float* __restrict__ c1b) {
  int blk = blockIdx.x;  // 256 = b*128 + og*4 + rt
  int rt = blk & 3;  blk >>= 2;
  int og = blk & 31; blk >>= 5;
  int b  = blk;
  int o0 = og * 2;
  int h0 = rt * 16;
  __shared__ __align__(16) float wl[1152];
  __shared__ __align__(16) float tile[2][18 * TRS];
  int t = threadIdx.x;
  for (int idx = t; idx < 1152; idx += 256) {
    int ch = idx / 18, rr = idx % 18;
    int k = rr >> 1, oo = rr & 1;
    wl[idx] = c1w[(size_t)(o0 + oo) * 576 + ch * 9 + k];
  }
  const float* in0 = ws + OB_OFF + (size_t)b * CN;
  int r = t >> 4, c0 = (t & 15) * 4;
  int ria = t >> 4, cia = (t & 15) * 4;
  int rib2 = 16 + (t >> 4);
  bool hasb = (t < 32);
  auto stage = [&](int ch, int ri, int ci) -> float4 {
    int hh = h0 - 1 + ri;
    float4 v = make_float4(0.f, 0.f, 0.f, 0.f);
    if (hh >= 0 && hh < 64) {
      float4 g = *reinterpret_cast<const float4*>(in0 + (size_t)ch * N_ + (size_t)hh * 64 + ci);
      v = make_float4(leaky(g.x), leaky(g.y), leaky(g.z), leaky(g.w));
    }
    return v;
  };
  float4 pfa = stage(0, ria, cia);
  float4 pfb = hasb ? stage(0, rib2, cia) : make_float4(0, 0, 0, 0);
  float acc[2][4] = {};
  for (int ch = 0; ch < 64; ++ch) {
    float* buf = tile[ch & 1];
    *reinterpret_cast<float4*>(&buf[ria * TRS + cia]) = pfa;
    if (hasb) *reinterpret_cast<float4*>(&buf[rib2 * TRS + cia]) = pfb;
    if (ch + 1 < 64) {
      pfa = stage(ch + 1, ria, cia);
      if (hasb) pfb = stage(ch + 1, rib2, cia);
    }
    __syncthreads();
#pragma unroll
    for (int ky = 0; ky < 3; ++ky) {
      int base = (r + ky) * TRS;
      float4 m = *reinterpret_cast<const float4*>(&buf[base + c0]);
      float left = (c0 > 0) ? buf[base + c0 - 1] : 0.f;
      float right = (c0 < 60) ? buf[base + c0 + 4] : 0.f;
      float t6[6] = {left, m.x, m.y, m.z, m.w, right};
#pragma unroll
      for (int kx = 0; kx < 3; ++kx) {
        float2 w2 = *reinterpret_cast<const float2*>(&wl[ch * 18 + (ky * 3 + kx) * 2]);
#pragma unroll
        for (int j = 0; j < 4; ++j) {
          float tp = t6[kx + j];
          acc[0][j] = fmaf(w2.x, tp, acc[0][j]);
          acc[1][j] = fmaf(w2.y, tp, acc[1][j]);
        }
      }
    }
  }
  size_t opix = (size_t)(h0 + r) * 64 + c0;
  float* ub = ws + UB_OFF + (size_t)b * CN;
#pragma unroll
  for (int oo = 0; oo < 2; ++oo) {
    float bb = c1b[o0 + oo];
    float4 o = make_float4(leaky(acc[oo][0] + bb), leaky(acc[oo][1] + bb),
                           leaky(acc[oo][2] + bb), leaky(acc[oo][3] + bb));
    *reinterpret_cast<float4*>(ub + (size_t)(o0 + oo) * N_ + opix) = o;
  }
}

// ---------------- K6: final, 2oc x 4px, dbuf + reg-prefetched ob ----------------
__global__ __launch_bounds__(256) void k_final(const float* __restrict__ ws,
                                               const float* __restrict__ c2w,
                                               const float* __restrict__ c2b,
                                               const float* __restrict__ scw,
                                               const float* __restrict__ scb,
                                               float* __restrict__ out) {
  int blk = blockIdx.x;  // 256 = b*128 + og*4 + rt
  int rt = blk & 3;  blk >>= 2;
  int og = blk & 31; blk >>= 5;
  int b  = blk;
  int o0 = og * 2;
  int h0 = rt * 16;
  __shared__ __align__(16) float wl[1152];
  __shared__ __align__(16) float scl[128];  // [ch][oo], oo=2
  __shared__ __align__(16) float tile[2][18 * TRS];
  int t = threadIdx.x;
  for (int idx = t; idx < 1152; idx += 256) {
    int ch = idx / 18, rr = idx % 18;
    int k = rr >> 1, oo = rr & 1;
    wl[idx] = c2w[(size_t)(o0 + oo) * 576 + ch * 9 + k];
  }
  if (t < 128) {
    int oo = t & 1, ch = t >> 1;
    scl[ch * 2 + oo] = scw[(size_t)(o0 + oo) * 64 + ch];
  }
  const float* u0 = ws + UB_OFF + (size_t)b * CN;
  const float* ob0 = ws + OB_OFF + (size_t)b * CN;
  int r = t >> 4, c0 = (t & 15) * 4;
  int ria = t >> 4, cia = (t & 15) * 4;
  int rib2 = 16 + (t >> 4);
  bool hasb = (t < 32);
  size_t mypix = (size_t)(h0 + r) * 64 + c0;
  auto stage = [&](int ch, int ri, int ci) -> float4 {
    int hh = h0 - 1 + ri;
    if (hh >= 0 && hh < 64)
      return *reinterpret_cast<const float4*>(u0 + (size_t)ch * N_ + (size_t)hh * 64 + ci);
    return make_float4(0.f, 0.f, 0.f, 0.f);
  };
  float4 pfa = stage(0, ria, cia);
  float4 pfb = hasb ? stage(0, rib2, cia) : make_float4(0, 0, 0, 0);
  float4 obc = *reinterpret_cast<const float4*>(ob0 + mypix);  // ch 0
  float acc[2][4] = {};
  float scp[2][4] = {};
  for (int ch = 0; ch < 64; ++ch) {
    float* buf = tile[ch & 1];
    *reinterpret_cast<float4*>(&buf[ria * TRS + cia]) = pfa;
    if (hasb) *reinterpret_cast<float4*>(&buf[rib2 * TRS + cia]) = pfb;
    float4 obn;
    if (ch + 1 < 64) {
      pfa = stage(ch + 1, ria, cia);
      if (hasb) pfb = stage(ch + 1, rib2, cia);
      obn = *reinterpret_cast<const float4*>(ob0 + (size_t)(ch + 1) * N_ + mypix);
    }
    __syncthreads();
#pragma unroll
    for (int ky = 0; ky < 3; ++ky) {
      int base = (r + ky) * TRS;
      float4 m = *reinterpret_cast<const float4*>(&buf[base + c0]);
      float left = (c0 > 0) ? buf[base + c0 - 1] : 0.f;
      float right = (c0 < 60) ? buf[base + c0 + 4] : 0.f;
      float t6[6] = {left, m.x, m.y, m.z, m.w, right};
#pragma unroll
      for (int kx = 0; kx < 3; ++kx) {
        float2 w2 = *reinterpret_cast<const float2*>(&wl[ch * 18 + (ky * 3 + kx) * 2]);
#pragma unroll
        for (int j = 0; j < 4; ++j) {
          float tp = t6[kx + j];
          acc[0][j] = fmaf(w2.x, tp, acc[0][j]);
          acc[1][j] = fmaf(w2.y, tp, acc[1][j]);
        }
      }
    }
    float2 s2 = *reinterpret_cast<const float2*>(&scl[ch * 2]);
    float obvv[4] = {obc.x, obc.y, obc.z, obc.w};
#pragma unroll
    for (int j = 0; j < 4; ++j) {
      scp[0][j] = fmaf(s2.x, obvv[j], scp[0][j]);
      scp[1][j] = fmaf(s2.y, obvv[j], scp[1][j]);
    }
    obc = obn;
  }
  const float* go = ws + GO_OFF + (size_t)b * CN;
  float* ob = out + (size_t)b * CN;
#pragma unroll
  for (int oo = 0; oo < 2; ++oo) {
    float c2bv = c2b[o0 + oo];
    float scbv = scb[o0 + oo];
    float4 gv = *reinterpret_cast<const float4*>(go + (size_t)(o0 + oo) * N_ + mypix);
    float4 o;
    o.x = (acc[oo][0] + c2bv) + (scp[oo][0] + scbv) * gv.x;
    o.y = (acc[oo][1] + c2bv) + (scp[oo][1] + scbv) * gv.y;
    o.z = (acc[oo][2] + c2bv) + (scp[oo][2] + scbv) * gv.z;
    o.w = (acc[oo][3] + c2bv) + (scp[oo][3] + scbv) * gv.w;
    *reinterpret_cast<float4*>(ob + (size_t)(o0 + oo) * N_ + mypix) = o;
  }
}

extern "C" void kernel_launch(void* const* d_in, const int* in_sizes, int n_in,
                              void* d_out, int out_size, void* d_ws, size_t ws_size,
                              hipStream_t stream) {
  const float* x     = (const float*)d_in[0];
  const float* guide = (const float*)d_in[1];
  const float* lin_w = (const float*)d_in[2];
  const float* lin_b = (const float*)d_in[3];
  const float* cw    = (const float*)d_in[4];
  const float* xq_w  = (const float*)d_in[5];
  const float* xq_b  = (const float*)d_in[6];
  const float* xk_w  = (const float*)d_in[7];
  const float* xk_b  = (const float*)d_in[8];
  const float* xv_w  = (const float*)d_in[9];
  const float* xv_b  = (const float*)d_in[10];
  const float* gq_w  = (const float*)d_in[11];
  const float* gq_b  = (const float*)d_in[12];
  const float* gk_w  = (const float*)d_in[13];
  const float* gk_b  = (const float*)d_in[14];
  const float* gamma = (const float*)d_in[15];
  const float* alpha = (const float*)d_in[16];
  const float* c1_w  = (const float*)d_in[17];
  const float* c1_b  = (const float*)d_in[18];
  const float* c2_w  = (const float*)d_in[19];
  const float* c2_b  = (const float*)d_in[20];
  const float* sc_w  = (const float*)d_in[21];
  const float* sc_b  = (const float*)d_in[22];
  float* out = (float*)d_out;
  float* ws = (float*)d_ws;

  k_coordconv<<<512, 256, 0, stream>>>(x, guide, lin_w, lin_b, cw, ws);
  k_proj<<<640, 256, 0, stream>>>(ws, xq_w, xq_b, xk_w, xk_b, xv_w, xv_b,
                                  gq_w, gq_b, gk_w, gk_b);
  k_attn<<<512, 256, 0, stream>>>(ws);
  k_merge<<<512, 256, 0, stream>>>(ws, gamma, alpha);
  k_conv1<<<256, 256, 0, stream>>>(ws, c1_w, c1_b);
  k_final<<<256, 256, 0, stream>>>(ws, c2_w, c2_b, sc_w, sc_b, out);
}